// Round 5
// baseline (1401.735 us; speedup 1.0000x reference)
//
// Round 5: kfix_attn ILP restructure (8 independent QK chains, 4 PV accumulators).
// Everything else unchanged from round 4.
#include <hip/hip_runtime.h>
#include <math.h>

#define TOK   4096
#define SEQL  1024
#define HID   512
#define NEXP  64
#define FFI   1536

typedef short bf16x8v __attribute__((ext_vector_type(8)));
typedef float f32x4   __attribute__((ext_vector_type(4)));

__device__ __forceinline__ unsigned short f2bf(float f){
  unsigned int u = __float_as_uint(f);
  u += 0x7fffu + ((u >> 16) & 1u);
  return (unsigned short)(u >> 16);
}
__device__ __forceinline__ float bf2f(unsigned short s){
  return __uint_as_float(((unsigned int)s) << 16);
}
__device__ __forceinline__ void split2(float v, unsigned short& h, unsigned short& l){
  h = f2bf(v);
  l = f2bf(v - bf2f(h));
}
// bijective chunked XCD swizzle over [0,total)
__device__ __forceinline__ int xcd_swizzle(int raw, int total){
  int q = total >> 3, r = total & 7;
  int xcd = raw & 7, pos = raw >> 3;
  int csz = (xcd < r) ? (q + 1) : q;
  if (pos >= csz) return -1;
  int basel = (xcd < r) ? xcd * (q + 1) : r * (q + 1) + (xcd - r) * q;
  return basel + pos;
}

// ---------------- elementwise split fp32 -> hi/lo bf16 ----------------
__global__ __launch_bounds__(256) void ksplit(const float* __restrict__ in,
    unsigned short* __restrict__ hi, unsigned short* __restrict__ lo, int n4){
  int g = blockIdx.x*256 + threadIdx.x;
  if (g >= n4) return;
  float4 v = *(const float4*)&in[(long long)g*4];
  unsigned short h0,h1,h2,h3,l0,l1,l2,l3;
  split2(v.x,h0,l0); split2(v.y,h1,l1); split2(v.z,h2,l2); split2(v.w,h3,l3);
  *(ushort4*)&hi[(long long)g*4] = make_ushort4(h0,h1,h2,h3);
  *(ushort4*)&lo[(long long)g*4] = make_ushort4(l0,l1,l2,l3);
}

// ---------------- transpose + split: fp32 [R][C] -> hi/lo bf16 [C][R] ----------------
__global__ __launch_bounds__(256) void kTsplit(const float* __restrict__ in,
    unsigned short* __restrict__ ohi, unsigned short* __restrict__ olo, int R, int C){
  __shared__ float tile[64][65];
  int c0 = blockIdx.x*64, r0 = blockIdx.y*64;
  int tid = threadIdx.x;
  #pragma unroll
  for (int it=0; it<4; it++){
    int idx = it*256+tid; int r = idx>>4; int cq = (idx&15)*4;
    float4 v = *(const float4*)&in[(long long)(r0+r)*C + c0 + cq];
    tile[r][cq]=v.x; tile[r][cq+1]=v.y; tile[r][cq+2]=v.z; tile[r][cq+3]=v.w;
  }
  __syncthreads();
  #pragma unroll
  for (int it=0; it<2; it++){
    int idx = it*256+tid; int c = idx>>3; int rq=(idx&7)*8;
    unsigned short th[8] __attribute__((aligned(16)));
    unsigned short tl[8] __attribute__((aligned(16)));
    #pragma unroll
    for (int j=0;j<8;j++) split2(tile[rq+j][c], th[j], tl[j]);
    long long o = (long long)(c0+c)*R + r0 + rq;
    *(uint4*)&ohi[o] = *(uint4*)th;
    *(uint4*)&olo[o] = *(uint4*)tl;
  }
}

// -------- weight convert+transpose fp32 [Z][R][C] -> bf16 [Z][C][R]; optional gate/up pairing --------
template<bool PAIRED>
__global__ __launch_bounds__(256) void kconvT(const float* __restrict__ in,
    unsigned short* __restrict__ out, int R, int C){
  __shared__ float tile[64][65];
  long long zb = (long long)blockIdx.z * R * C;
  int c0 = blockIdx.x*64, r0 = blockIdx.y*64;
  int tid = threadIdx.x;
  #pragma unroll
  for (int it=0; it<4; it++){
    int idx = it*256+tid; int r = idx>>4; int cq = (idx&15)*4;
    float4 v = *(const float4*)&in[zb + (long long)(r0+r)*C + c0 + cq];
    tile[r][cq]=v.x; tile[r][cq+1]=v.y; tile[r][cq+2]=v.z; tile[r][cq+3]=v.w;
  }
  __syncthreads();
  #pragma unroll
  for (int it=0; it<2; it++){
    int idx = it*256+tid; int c = idx>>3; int rq=(idx&7)*8;
    unsigned short tb[8] __attribute__((aligned(16)));
    #pragma unroll
    for (int j=0;j<8;j++) tb[j] = f2bf(tile[rq+j][c]);
    int cc = c0 + c;
    int orow = PAIRED ? ((cc < (C>>1)) ? 2*cc : 2*(cc-(C>>1))+1) : cc;
    *(uint4*)&out[zb + (long long)orow*R + r0 + rq] = *(uint4*)tb;
  }
}

// ---------------- bf16x3 TN GEMM: C = alpha * (Ahi+Alo)(Bhi+Blo)^T (drop lo*lo) ----------------
template<int WM,int WN,int FM,int FN>
__global__ __launch_bounds__(256) void gemm_x3(
    const unsigned short* __restrict__ Ahi, const unsigned short* __restrict__ Alo,
    const unsigned short* __restrict__ Bhi, const unsigned short* __restrict__ Blo,
    float* __restrict__ C, int K, int lda, int ldb, int ldc, float alpha,
    long long a1, long long a2, int adiv,
    long long b1, long long b2, int bdiv,
    long long c1, long long c2, int cdiv)
{
  constexpr int BM = WM*FM*16, BN = WN*FN*16;
  constexpr int AIT = (2*BM*4)/256, BIT = (2*BN*4)/256;
  int z = blockIdx.z;
  long long aoff = (long long)(z/adiv)*a1 + (long long)(z%adiv)*a2;
  long long boff = (long long)(z/bdiv)*b1 + (long long)(z%bdiv)*b2;
  C += (long long)(z/cdiv)*c1 + (long long)(z%cdiv)*c2;
  int m0 = blockIdx.x*BM, n0 = blockIdx.y*BN;
  __shared__ __align__(16) unsigned short As[2][BM*40];
  __shared__ __align__(16) unsigned short Bs[2][BN*40];
  int tid = threadIdx.x, lane = tid&63, wid = tid>>6;
  int wr = wid / WN, wc = wid % WN;
  int lrow = lane&15, kgo = (lane>>4)*8;
  f32x4 acc[FM][FN];
  #pragma unroll
  for (int mi=0;mi<FM;mi++)
    #pragma unroll
    for (int nj=0;nj<FN;nj++) acc[mi][nj] = (f32x4){0.f,0.f,0.f,0.f};

  for (int k0=0; k0<K; k0+=32){
    uint4 ta[AIT], tb[BIT];
    #pragma unroll
    for (int it=0; it<AIT; it++){
      int c = it*256+tid; int pl = c/(BM*4); int rem = c%(BM*4);
      int row = rem>>2, q = (rem&3)*8;
      const unsigned short* src = pl ? Alo : Ahi;
      ta[it] = *(const uint4*)&src[aoff + (long long)(m0+row)*lda + k0 + q];
    }
    #pragma unroll
    for (int it=0; it<BIT; it++){
      int c = it*256+tid; int pl = c/(BN*4); int rem = c%(BN*4);
      int row = rem>>2, q = (rem&3)*8;
      const unsigned short* src = pl ? Blo : Bhi;
      tb[it] = *(const uint4*)&src[boff + (long long)(n0+row)*ldb + k0 + q];
    }
    __syncthreads();
    #pragma unroll
    for (int it=0; it<AIT; it++){
      int c = it*256+tid; int pl = c/(BM*4); int rem = c%(BM*4);
      int row = rem>>2, q = (rem&3)*8;
      *(uint4*)&As[pl][row*40+q] = ta[it];
    }
    #pragma unroll
    for (int it=0; it<BIT; it++){
      int c = it*256+tid; int pl = c/(BN*4); int rem = c%(BN*4);
      int row = rem>>2, q = (rem&3)*8;
      *(uint4*)&Bs[pl][row*40+q] = tb[it];
    }
    __syncthreads();
    bf16x8v ah[FM], al[FM], bh[FN], bl[FN];
    int ab = (wr*FM*16 + lrow)*40 + kgo;
    int bb = (wc*FN*16 + lrow)*40 + kgo;
    #pragma unroll
    for (int mi=0;mi<FM;mi++){
      ah[mi] = *(const bf16x8v*)&As[0][ab + mi*640];
      al[mi] = *(const bf16x8v*)&As[1][ab + mi*640];
    }
    #pragma unroll
    for (int nj=0;nj<FN;nj++){
      bh[nj] = *(const bf16x8v*)&Bs[0][bb + nj*640];
      bl[nj] = *(const bf16x8v*)&Bs[1][bb + nj*640];
    }
    #pragma unroll
    for (int mi=0;mi<FM;mi++)
      #pragma unroll
      for (int nj=0;nj<FN;nj++){
        acc[mi][nj] = __builtin_amdgcn_mfma_f32_16x16x32_bf16(ah[mi], bh[nj], acc[mi][nj], 0,0,0);
        acc[mi][nj] = __builtin_amdgcn_mfma_f32_16x16x32_bf16(ah[mi], bl[nj], acc[mi][nj], 0,0,0);
        acc[mi][nj] = __builtin_amdgcn_mfma_f32_16x16x32_bf16(al[mi], bh[nj], acc[mi][nj], 0,0,0);
      }
  }
  int crow = m0 + wr*FM*16 + ((lane>>4)<<2);
  int ccol = n0 + wc*FN*16 + (lane&15);
  #pragma unroll
  for (int mi=0;mi<FM;mi++)
    #pragma unroll
    for (int r=0;r<4;r++){
      long long row = crow + mi*16 + r;
      #pragma unroll
      for (int nj=0;nj<FN;nj++)
        C[row*ldc + ccol + nj*16] = alpha*acc[mi][nj][r];
    }
}

// ---------------- RoPE: rotate q,k in fp32 (write back) + split to hi/lo ----------------
__global__ __launch_bounds__(256) void krope(float* __restrict__ qkv,
    unsigned short* __restrict__ qhi, unsigned short* __restrict__ qlo,
    const float* __restrict__ cosb, const float* __restrict__ sinb){
  int gid = blockIdx.x*256 + threadIdx.x;
  int t = gid >> 8; int rem = gid & 255; int h = rem >> 5; int d = rem & 31;
  int s = t & (SEQL-1);
  long long base = (long long)t*1536 + h*64;
  float c1 = cosb[s*64+d], c2 = cosb[s*64+d+32];
  float s1 = sinb[s*64+d], s2 = sinb[s*64+d+32];
  float q1 = qkv[base+d], q2 = qkv[base+d+32];
  float rq1 = q1*c1 - q2*s1, rq2 = q2*c2 + q1*s2;
  qkv[base+d] = rq1; qkv[base+d+32] = rq2;
  split2(rq1, qhi[base+d],    qlo[base+d]);
  split2(rq2, qhi[base+d+32], qlo[base+d+32]);
  float k1 = qkv[base+512+d], k2 = qkv[base+512+d+32];
  float rk1 = k1*c1 - k2*s1, rk2 = k2*c2 + k1*s2;
  qkv[base+512+d] = rk1; qkv[base+512+d+32] = rk2;
  split2(rk1, qhi[base+512+d],    qlo[base+512+d]);
  split2(rk2, qhi[base+512+d+32], qlo[base+512+d+32]);
}

// ---------------- V transpose ----------------
__global__ __launch_bounds__(256) void kvtrans(const float* __restrict__ qkv,
    unsigned short* __restrict__ vhi, unsigned short* __restrict__ vlo){
  __shared__ float tile[64][65];
  int s0 = blockIdx.x*64;
  int z = blockIdx.y;
  int b = z >> 3, h = z & 7;
  int tid = threadIdx.x;
  #pragma unroll
  for (int it=0; it<4; it++){
    int idx = it*256+tid; int r = idx>>4; int cq = (idx&15)*4;
    float4 v = *(const float4*)&qkv[((long long)(b*1024 + s0 + r))*1536 + 1024 + h*64 + cq];
    tile[r][cq]=v.x; tile[r][cq+1]=v.y; tile[r][cq+2]=v.z; tile[r][cq+3]=v.w;
  }
  __syncthreads();
  #pragma unroll
  for (int it=0; it<2; it++){
    int idx = it*256+tid; int d = idx>>3; int sq = (idx&7)*8;
    unsigned short th[8] __attribute__((aligned(16)));
    unsigned short tl[8] __attribute__((aligned(16)));
    #pragma unroll
    for (int j=0;j<8;j++) split2(tile[sq+j][d], th[j], tl[j]);
    long long o = ((long long)(z*64 + d))*1024 + s0 + sq;
    *(uint4*)&vhi[o] = *(uint4*)th;
    *(uint4*)&vlo[o] = *(uint4*)tl;
  }
}

// ---------------- softmax rows of 1024, output split bf16 ----------------
__global__ __launch_bounds__(256) void ksoftmax(const float* __restrict__ sc,
    unsigned short* __restrict__ phi, unsigned short* __restrict__ plo){
  long long row = blockIdx.x;
  const float* p = sc + row*1024;
  int tid = threadIdx.x;
  float4 v = *(const float4*)&p[tid*4];
  float m = fmaxf(fmaxf(v.x,v.y), fmaxf(v.z,v.w));
  for (int o=32;o>0;o>>=1) m = fmaxf(m, __shfl_xor(m,o));
  __shared__ float redm[4], reds[4];
  int wid = tid>>6, lane = tid&63;
  if (lane==0) redm[wid]=m;
  __syncthreads();
  m = fmaxf(fmaxf(redm[0],redm[1]), fmaxf(redm[2],redm[3]));
  float e0=expf(v.x-m), e1=expf(v.y-m), e2=expf(v.z-m), e3=expf(v.w-m);
  float sum = e0+e1+e2+e3;
  for (int o=32;o>0;o>>=1) sum += __shfl_xor(sum,o);
  if (lane==0) reds[wid]=sum;
  __syncthreads();
  sum = reds[0]+reds[1]+reds[2]+reds[3];
  float inv = 1.0f/sum;
  unsigned short h0,h1,h2,h3,l0,l1,l2,l3;
  split2(e0*inv,h0,l0); split2(e1*inv,h1,l1); split2(e2*inv,h2,l2); split2(e3*inv,h3,l3);
  *(ushort4*)&phi[row*1024 + tid*4] = make_ushort4(h0,h1,h2,h3);
  *(ushort4*)&plo[row*1024 + tid*4] = make_ushort4(l0,l1,l2,l3);
}

// ---------------- rms_norm(x+attn) -> h1 hi/lo + h1b + hbuf(f32) ----------------
__global__ __launch_bounds__(128) void krms1(const float* __restrict__ x, const float* __restrict__ attn,
    unsigned short* __restrict__ h1hi, unsigned short* __restrict__ h1lo,
    unsigned short* __restrict__ h1b, float* __restrict__ hbuf){
  long long row = blockIdx.x;
  int tid = threadIdx.x;
  float4 xv = *(const float4*)&x[row*512 + tid*4];
  float4 av = *(const float4*)&attn[row*512 + tid*4];
  float4 v; v.x=xv.x+av.x; v.y=xv.y+av.y; v.z=xv.z+av.z; v.w=xv.w+av.w;
  float ss = v.x*v.x + v.y*v.y + v.z*v.z + v.w*v.w;
  for (int o=32;o>0;o>>=1) ss += __shfl_xor(ss,o);
  __shared__ float red[2];
  int wid = tid>>6, lane = tid&63;
  if (lane==0) red[wid]=ss;
  __syncthreads();
  ss = red[0]+red[1];
  float r = 1.0f/sqrtf(ss*(1.0f/512.0f) + 1e-5f);
  float4 o; o.x=v.x*r; o.y=v.y*r; o.z=v.z*r; o.w=v.w*r;
  *(float4*)&hbuf[row*512 + tid*4] = o;
  unsigned short h0,h1,h2,h3,l0,l1,l2,l3;
  split2(o.x,h0,l0); split2(o.y,h1,l1); split2(o.z,h2,l2); split2(o.w,h3,l3);
  *(ushort4*)&h1hi[row*512 + tid*4] = make_ushort4(h0,h1,h2,h3);
  *(ushort4*)&h1lo[row*512 + tid*4] = make_ushort4(l0,l1,l2,l3);
  *(ushort4*)&h1b[row*512 + tid*4] = make_ushort4(f2bf(o.x),f2bf(o.y),f2bf(o.z),f2bf(o.w));
}

// ---------------- routing decision (one 64-lane wave per token) ----------------
__device__ void route_decide(float p, int e, int t,
    int* __restrict__ idx, float* __restrict__ wts,
    int* __restrict__ flagcnt, int* __restrict__ flaglist){
  float d = p;
  d += __shfl_xor(d,1); d += __shfl_xor(d,2); d += __shfl_xor(d,4);
  int g = e >> 3;
  float gs[8];
  #pragma unroll
  for (int j=0;j<8;j++) gs[j] = __shfl(d, j*8);
  int rank = 0;
  #pragma unroll
  for (int j=0;j<8;j++) rank += (gs[j] > d) || (gs[j] == d && j < g);
  float q = (rank < 3) ? p : -INFINITY;
  float svals[7]; int sidx[7];
  #pragma unroll
  for (int kk=0; kk<7; kk++){
    float v = q; int vi = e;
    for (int o=32;o>0;o>>=1){
      float ov = __shfl_xor(v,o); int oi = __shfl_xor(vi,o);
      if (ov > v || (ov == v && oi < vi)){ v = ov; vi = oi; }
    }
    svals[kk] = v; sidx[kk] = vi;
    if (e == vi) q = -INFINITY;
  }
  float mx = svals[0], tot = 0.f, wv[6];
  #pragma unroll
  for (int kk=0;kk<6;kk++){ wv[kk] = expf(svals[kk]-mx); tot += wv[kk]; }
  if (e < 6){
    idx[t*6+e] = sidx[e];
    wts[t*6+e] = wv[e]/tot;
  }
  if (flagcnt != nullptr && e == 0){
    float a[8];
    #pragma unroll
    for (int j=0;j<8;j++) a[j] = gs[j];
    float t3=-1e30f, t4=-1e30f;
    for (int it2=0; it2<4; it2++){
      int bi=0; float bv=a[0];
      #pragma unroll
      for (int j=1;j<8;j++) if (a[j] > bv){ bv=a[j]; bi=j; }
      if (it2==2) t3=bv;
      if (it2==3) t4=bv;
      a[bi] = -1e30f;
    }
    float pgap = svals[5] - svals[6];
    float dgap = t3 - t4;
    if (pgap < 1e-4f || dgap < 5e-4f){
      int pos = atomicAdd(flagcnt, 1);
      if (pos < 1024) flaglist[pos] = t;
    }
  }
}

__global__ __launch_bounds__(256) void krouter(const float* __restrict__ logits,
    float* __restrict__ probs, int* __restrict__ idx, float* __restrict__ wts,
    int* __restrict__ flagcnt, int* __restrict__ flaglist){
  int t = blockIdx.x*4 + (threadIdx.x >> 6);
  int e = threadIdx.x & 63;
  float l = logits[t*64 + e];
  float m = l;
  for (int o=32;o>0;o>>=1) m = fmaxf(m, __shfl_xor(m,o));
  float p = expf(l-m);
  float s = p;
  for (int o=32;o>0;o>>=1) s += __shfl_xor(s,o);
  p /= s;
  probs[t*64+e] = p;
  route_decide(p, e, t, idx, wts, flagcnt, flaglist);
}

// ---------------- exact fp32 attention recompute, one block per (flag, head), 8-way ILP ----------------
__global__ __launch_bounds__(256) void kfix_attn(const int* __restrict__ flagcnt,
    const int* __restrict__ flaglist, const float* __restrict__ qkv, float* __restrict__ fixo){
  int fc = *flagcnt; if (fc > 1024) fc = 1024;
  if ((int)blockIdx.x >= fc) return;
  int t = flaglist[blockIdx.x];
  int h = blockIdx.y;
  int b = t >> 10;
  int tid = threadIdx.x, lane = tid & 63, w = tid >> 6;
  __shared__ float sc[1024];
  __shared__ float qh[64];
  __shared__ float red[4];
  __shared__ float op[4][64];
  __shared__ float sinv;
  if (tid < 64) qh[tid] = qkv[(long long)t*1536 + h*64 + tid];
  __syncthreads();
  float q = qh[lane];
  const float* kb = qkv + (long long)b*1024*1536 + 512 + h*64 + lane;
  // QK: 8 independent rows per step -> 8 loads in flight, 8 parallel shfl chains
  for (int s0 = w*256; s0 < w*256 + 256; s0 += 8){
    float p[8];
    #pragma unroll
    for (int j=0;j<8;j++) p[j] = q * kb[(long long)(s0+j)*1536];
    #pragma unroll
    for (int o=32;o>0;o>>=1){
      #pragma unroll
      for (int j=0;j<8;j++) p[j] += __shfl_xor(p[j],o);
    }
    if (lane == 0){
      #pragma unroll
      for (int j=0;j<8;j++) sc[s0+j] = p[j] * 0.125f;
    }
  }
  __syncthreads();
  // softmax over sc[1024]
  float m = -1e30f;
  for (int s = tid; s < 1024; s += 256) m = fmaxf(m, sc[s]);
  #pragma unroll
  for (int o=32;o>0;o>>=1) m = fmaxf(m, __shfl_xor(m,o));
  if (lane == 0) red[w] = m;
  __syncthreads();
  m = fmaxf(fmaxf(red[0],red[1]), fmaxf(red[2],red[3]));
  __syncthreads();
  float sum = 0.f;
  for (int s = tid; s < 1024; s += 256){ float e = expf(sc[s]-m); sc[s] = e; sum += e; }
  #pragma unroll
  for (int o=32;o>0;o>>=1) sum += __shfl_xor(sum,o);
  if (lane == 0) red[w] = sum;
  __syncthreads();
  if (tid == 0) sinv = 1.0f/(red[0]+red[1]+red[2]+red[3]);
  // PV: 4 independent accumulator chains, coalesced V loads
  const float* vb = qkv + (long long)b*1024*1536 + 1024 + h*64 + lane;
  float a0 = 0.f, a1 = 0.f, a2 = 0.f, a3 = 0.f;
  for (int s = w*256; s < w*256 + 256; s += 4){
    a0 += sc[s]   * vb[(long long)(s)*1536];
    a1 += sc[s+1] * vb[(long long)(s+1)*1536];
    a2 += sc[s+2] * vb[(long long)(s+2)*1536];
    a3 += sc[s+3] * vb[(long long)(s+3)*1536];
  }
  op[w][lane] = (a0+a1)+(a2+a3);
  __syncthreads();
  if (tid < 64)
    fixo[(long long)blockIdx.x*512 + h*64 + tid] =
      (op[0][tid]+op[1][tid]+op[2][tid]+op[3][tid]) * sinv;
}

// ---------------- exact fp32 w_o + rms + router for flagged tokens ----------------
__global__ __launch_bounds__(256) void kfix_route(const int* __restrict__ flagcnt,
    const int* __restrict__ flaglist, const float* __restrict__ fixo,
    const float* __restrict__ x, const float* __restrict__ w_o, const float* __restrict__ router_w,
    int* __restrict__ idx, float* __restrict__ wts, float* __restrict__ probs){
  int fc = *flagcnt; if (fc > 1024) fc = 1024;
  if ((int)blockIdx.x >= fc) return;
  int t = flaglist[blockIdx.x];
  int tid = threadIdx.x;
  __shared__ float o512[512];
  __shared__ float h1s[512];
  __shared__ float red[4];
  o512[tid]     = fixo[(long long)blockIdx.x*512 + tid];
  o512[tid+256] = fixo[(long long)blockIdx.x*512 + tid + 256];
  __syncthreads();
  int j0 = tid, j1 = tid + 256;
  float a0 = 0.f, a1 = 0.f;
  #pragma unroll 4
  for (int i = 0; i < 512; i++){
    float oi = o512[i];
    a0 += oi * w_o[(long long)i*512 + j0];
    a1 += oi * w_o[(long long)i*512 + j1];
  }
  float hj0 = x[(long long)t*512 + j0] + a0;
  float hj1 = x[(long long)t*512 + j1] + a1;
  float ss = hj0*hj0 + hj1*hj1;
  #pragma unroll
  for (int o=32;o>0;o>>=1) ss += __shfl_xor(ss,o);
  if ((tid&63)==0) red[tid>>6]=ss;
  __syncthreads();
  ss = red[0]+red[1]+red[2]+red[3];
  float r = 1.0f/sqrtf(ss*(1.0f/512.0f) + 1e-5f);
  h1s[j0] = hj0*r; h1s[j1] = hj1*r;
  __syncthreads();
  if (tid < 64){
    int e = tid;
    float le = 0.f;
    #pragma unroll 4
    for (int i=0;i<512;i++) le += h1s[i]*router_w[(long long)i*64 + e];
    float m2 = le;
    #pragma unroll
    for (int o=32;o>0;o>>=1) m2 = fmaxf(m2, __shfl_xor(m2,o));
    float p = expf(le - m2), s2 = p;
    #pragma unroll
    for (int o=32;o>0;o>>=1) s2 += __shfl_xor(s2,o);
    p /= s2;
    probs[(long long)t*64 + e] = p;
    route_decide(p, e, t, idx, wts, nullptr, nullptr);
  }
}

__global__ void kcount(const int* __restrict__ idx, int* __restrict__ cnt){
  int g = blockIdx.x*256 + threadIdx.x;
  if (g < TOK*6) atomicAdd(&cnt[idx[g]], 1);
}

__global__ __launch_bounds__(256) void ksump(const float* __restrict__ probs, float* __restrict__ sumP){
  int e = blockIdx.x; int tid = threadIdx.x;
  float acc = 0.f;
  for (int t = tid; t < TOK; t += 256) acc += probs[t*64 + e];
  for (int o=32;o>0;o>>=1) acc += __shfl_xor(acc,o);
  __shared__ float red[4];
  int wid = tid>>6, lane = tid&63;
  if (lane==0) red[wid]=acc;
  __syncthreads();
  if (tid==0) sumP[e] = red[0]+red[1]+red[2]+red[3];
}

__global__ void kfinalize(const int* __restrict__ cnt, int* __restrict__ offs,
                          int2* __restrict__ tiles, int* __restrict__ ntl){
  if (threadIdx.x == 0){
    int acc = 0;
    for (int e=0;e<64;e++){ offs[e]=acc; acc += cnt[e]; }
    offs[64]=acc;
    int nt = 0;
    for (int e=0;e<64;e++){
      int me = cnt[e];
      for (int m0=0;m0<me;m0+=128){ tiles[nt] = make_int2(e,m0); nt++; }
    }
    *ntl = nt;
  }
}

__global__ __launch_bounds__(256) void kscatter(const int* __restrict__ idx, const float* __restrict__ wts,
    const int* __restrict__ offs, int* __restrict__ cursor,
    int* __restrict__ rowsl, float* __restrict__ wrowl, int* __restrict__ slot_of){
  int g = blockIdx.x*256 + threadIdx.x;
  if (g >= TOK*6) return;
  int t = g/6, kk = g%6;
  int e = idx[t*6+kk];
  int pos = atomicAdd(&cursor[e], 1);
  int slot = offs[e]+pos;
  rowsl[slot] = t;
  wrowl[slot] = wts[t*6+kk];
  slot_of[t*6+kk] = slot;
}

__global__ __launch_bounds__(256) void kgather(const unsigned short* __restrict__ h1b,
    const int* __restrict__ rowsl, unsigned short* __restrict__ xg){
  int r = blockIdx.x*4 + (threadIdx.x>>6);
  int lane = threadIdx.x&63;
  int tok = rowsl[r];
  *(uint4*)&xg[(long long)r*512 + lane*8] = *(const uint4*)&h1b[(long long)tok*512 + lane*8];
}

// ---------------- FFN bf16 MFMA GEMM (128x128, BK=32) ----------------
template<int MODE>
__global__ __launch_bounds__(256) void gemm_ffn(
    const unsigned short* __restrict__ Ab, const unsigned short* __restrict__ Bw,
    unsigned short* __restrict__ Cact, float* __restrict__ Cd,
    const int* __restrict__ offs, const int2* __restrict__ tiles, const int* __restrict__ ntl,
    int N, int K)
{
  int e=0, m0=0, roff=0, Me=1<<30, n0=0, zi=0;
  long long Aoff=0, Boff=0;
  int lda;
  if constexpr (MODE==0 || MODE==1){
    constexpr int NF = (MODE==0) ? 24 : 4;
    int nt = *ntl;
    int total = nt*NF;
    int l = xcd_swizzle(blockIdx.x, total);
    if (l < 0 || l >= total) return;
    int tile = l / NF; int y = l % NF;
    int2 tl = tiles[tile];
    e = tl.x; m0 = tl.y;
    roff = offs[e]; Me = offs[e+1]-roff;
    n0 = y*128;
    Boff = (long long)e*N*K;
    lda = K;
  } else {
    m0 = blockIdx.x*128;
    n0 = blockIdx.y*128;
    zi = blockIdx.z;
    Boff = (long long)zi*N*K;
    if constexpr (MODE==2) lda = 512;
    else { lda = K; Aoff = (long long)zi*4096*K; }
  }
  __shared__ __align__(16) unsigned short As[128*40];
  __shared__ __align__(16) unsigned short Bs[128*40];
  int tid = threadIdx.x, lane = tid&63, wid = tid>>6;
  int wr = wid>>1, wc = wid&1;
  int lrow = lane&15, kgo = (lane>>4)*8;
  f32x4 acc[4][4];
  #pragma unroll
  for (int mi=0;mi<4;mi++)
    #pragma unroll
    for (int nj=0;nj<4;nj++) acc[mi][nj] = (f32x4){0.f,0.f,0.f,0.f};

  int arow0 = tid>>2, q0 = (tid&3)*8;
  long long abase0, abase1;
  {
    if constexpr (MODE==0 || MODE==1){
      int r0i = roff + m0 + arow0; if (r0i > 24575) r0i = 24575;
      int r1i = roff + m0 + arow0 + 64; if (r1i > 24575) r1i = 24575;
      abase0 = (long long)r0i*lda; abase1 = (long long)r1i*lda;
    } else if constexpr (MODE==2){
      abase0 = (long long)(m0+arow0)*lda; abase1 = (long long)(m0+arow0+64)*lda;
    } else {
      abase0 = Aoff + (long long)(m0+arow0)*lda; abase1 = Aoff + (long long)(m0+arow0+64)*lda;
    }
  }

  for (int k0=0; k0<K; k0+=32){
    uint4 ta0 = *(const uint4*)&Ab[abase0 + k0 + q0];
    uint4 ta1 = *(const uint4*)&Ab[abase1 + k0 + q0];
    uint4 tb0 = *(const uint4*)&Bw[Boff + (long long)(n0+arow0)*K + k0 + q0];
    uint4 tb1 = *(const uint4*)&Bw[Boff + (long long)(n0+arow0+64)*K + k0 + q0];
    __syncthreads();
    *(uint4*)&As[arow0*40+q0]      = ta0;
    *(uint4*)&As[(arow0+64)*40+q0] = ta1;
    *(uint4*)&Bs[arow0*40+q0]      = tb0;
    *(uint4*)&Bs[(arow0+64)*40+q0] = tb1;
    __syncthreads();
    bf16x8v af[4], bfv[4];
    int ab = (wr*64 + lrow)*40 + kgo;
    int bb = (wc*64 + lrow)*40 + kgo;
    #pragma unroll
    for (int mi=0;mi<4;mi++) af[mi]  = *(const bf16x8v*)&As[ab + mi*640];
    #pragma unroll
    for (int nj=0;nj<4;nj++) bfv[nj] = *(const bf16x8v*)&Bs[bb + nj*640];
    #pragma unroll
    for (int mi=0;mi<4;mi++)
      #pragma unroll
      for (int nj=0;nj<4;nj++)
        acc[mi][nj] = __builtin_amdgcn_mfma_f32_16x16x32_bf16(af[mi], bfv[nj], acc[mi][nj], 0,0,0);
  }

  int lq = lane>>4;
  int l15 = lane&15;
  if constexpr (MODE==0 || MODE==2){
    bool evenlane = (l15&1)==0;
    int pb = (n0>>1) + wc*32 + (l15>>1);
    #pragma unroll
    for (int mi=0;mi<4;mi++){
      #pragma unroll
      for (int r2=0;r2<4;r2++){
        int lr = wr*64 + mi*16 + lq*4 + r2;
        bool valid; long long grow;
        if constexpr (MODE==0){ valid = (m0+lr)<Me; grow = roff+m0+lr; }
        else { valid = true; grow = (long long)zi*4096 + m0 + lr; }
        #pragma unroll
        for (int nj=0;nj<4;nj++){
          float v = acc[mi][nj][r2];
          float o2 = __shfl_xor(v,1);
          if (evenlane && valid){
            float g = v, u = o2;
            float sg = g/(1.0f+expf(-g))*u;
            Cact[grow*1536 + pb + nj*8] = f2bf(sg);
          }
        }
      }
    }
  } else {
    #pragma unroll
    for (int mi=0;mi<4;mi++)
      #pragma unroll
      for (int r2=0;r2<4;r2++){
        int lr = wr*64 + mi*16 + lq*4 + r2;
        bool valid; long long grow;
        if constexpr (MODE==1){ valid = (m0+lr)<Me; grow = roff+m0+lr; }
        else { valid = true; grow = (long long)zi*4096 + m0 + lr; }
        if (valid){
          #pragma unroll
          for (int nj=0;nj<4;nj++)
            Cd[grow*512 + n0 + wc*64 + nj*16 + l15] = acc[mi][nj][r2];
        }
      }
  }
}

// ---------------- final reduce: out = rms(h1 + shared + routed) ----------------
__global__ __launch_bounds__(128) void kreduce(const float* __restrict__ hbuf,
    const float* __restrict__ sdout, const float* __restrict__ dout,
    const int* __restrict__ slot_of, const float* __restrict__ wts,
    float* __restrict__ out){
  int t = blockIdx.x;
  int tid = threadIdx.x;
  int c4 = tid*4;
  float4 s = *(const float4*)&hbuf[(long long)t*512 + c4];
  float4 a = *(const float4*)&sdout[(long long)t*512 + c4];
  float4 b = *(const float4*)&sdout[(long long)(4096+t)*512 + c4];
  s.x += a.x + b.x; s.y += a.y + b.y; s.z += a.z + b.z; s.w += a.w + b.w;
  #pragma unroll
  for (int kk=0; kk<6; kk++){
    float w = wts[t*6+kk];
    int slot = slot_of[t*6+kk];
    float4 d = *(const float4*)&dout[(long long)slot*512 + c4];
    s.x += w*d.x; s.y += w*d.y; s.z += w*d.z; s.w += w*d.w;
  }
  float ss = s.x*s.x + s.y*s.y + s.z*s.z + s.w*s.w;
  for (int o=32;o>0;o>>=1) ss += __shfl_xor(ss,o);
  __shared__ float red[2];
  int wid = tid>>6, lane = tid&63;
  if (lane==0) red[wid]=ss;
  __syncthreads();
  ss = red[0]+red[1];
  float r = 1.0f/sqrtf(ss*(1.0f/512.0f) + 1e-5f);
  float4 o; o.x=s.x*r; o.y=s.y*r; o.z=s.z*r; o.w=s.w*r;
  *(float4*)&out[(long long)t*512 + c4] = o;
}

// ---------------- balance-loss scalars ----------------
__global__ void kscalars(const int* __restrict__ cnt, const float* __restrict__ sumP, float* __restrict__ o){
  int e = threadIdx.x;
  float cf = (float)cnt[e];
  float f = cf / 24576.0f;
  float P = sumP[e] / 4096.0f;
  float fg = f, Pg = P, cg = cf;
  fg += __shfl_xor(fg,1); fg += __shfl_xor(fg,2); fg += __shfl_xor(fg,4);
  Pg += __shfl_xor(Pg,1); Pg += __shfl_xor(Pg,2); Pg += __shfl_xor(Pg,4);
  cg += __shfl_xor(cg,1); cg += __shfl_xor(cg,2); cg += __shfl_xor(cg,4);
  float t1 = f*P;
  float t2 = ((e&7)==0) ? (fg/8.0f)*Pg : 0.0f;
  float t3 = ((e&7)==0) ? (cg/12288.0f)*Pg : 0.0f;
  for (int s=32;s>0;s>>=1){
    t1 += __shfl_xor(t1,s); t2 += __shfl_xor(t2,s); t3 += __shfl_xor(t3,s);
  }
  if (e==0){
    float ebl = t1*0.003f, dbl = t2*0.05f, cbl = t3*0.02f;
    o[0]=ebl; o[1]=dbl; o[2]=cbl; o[3]=ebl+dbl+cbl;
  }
}

// ---------------- launch ----------------
extern "C" void kernel_launch(void* const* d_in, const int* in_sizes, int n_in,
                              void* d_out, int out_size, void* d_ws, size_t ws_size,
                              hipStream_t stream){
  const float* x        = (const float*)d_in[0];
  const float* cosb     = (const float*)d_in[1];
  const float* sinb     = (const float*)d_in[2];
  const float* w_qkv    = (const float*)d_in[3];
  const float* w_o      = (const float*)d_in[4];
  const float* router_w = (const float*)d_in[5];
  const float* r_wgu    = (const float*)d_in[6];
  const float* r_wd     = (const float*)d_in[7];
  const float* s_wgu    = (const float*)d_in[8];
  const float* s_wd     = (const float*)d_in[9];
  float* out = (float*)d_out;

  char* base = (char*)d_ws;
  size_t off = 0;
  auto alloc = [&](size_t b)->char*{
    char* p = base + off; off = (off + b + 255) & ~(size_t)255; return p;
  };
  // persistent
  unsigned short* x_hi   = (unsigned short*)alloc(2097152ULL*2);
  unsigned short* x_lo   = (unsigned short*)alloc(2097152ULL*2);
  unsigned short* wqkvT_hi = (unsigned short*)alloc(786432ULL*2);
  unsigned short* wqkvT_lo = (unsigned short*)alloc(786432ULL*2);
  unsigned short* woT_hi = (unsigned short*)alloc(262144ULL*2);
  unsigned short* woT_lo = (unsigned short*)alloc(262144ULL*2);
  unsigned short* wrT_hi = (unsigned short*)alloc(32768ULL*2);
  unsigned short* wrT_lo = (unsigned short*)alloc(32768ULL*2);
  unsigned short* h1_hi  = (unsigned short*)alloc(2097152ULL*2);
  unsigned short* h1_lo  = (unsigned short*)alloc(2097152ULL*2);
  unsigned short* h1b    = (unsigned short*)alloc(2097152ULL*2);
  float* hbuf   = (float*)alloc(2097152ULL*4);
  float* fixo   = (float*)alloc(1024ULL*512*4);
  float* logits = (float*)alloc(262144ULL*4);
  float* probs  = (float*)alloc(262144ULL*4);
  int*   idx    = (int*)alloc(24576ULL*4);
  float* wts    = (float*)alloc(24576ULL*4);
  int*   slot_of= (int*)alloc(24576ULL*4);
  int*   cnt     = (int*)alloc(256);
  int*   cursor  = (int*)alloc(256);
  int*   flagcnt = (int*)alloc(256);
  int*   flaglist= (int*)alloc(1024*4);
  int*   offs   = (int*)alloc(65*4);
  int*   ntl    = (int*)alloc(256);
  float* sumP   = (float*)alloc(64*4);
  int2*  tiles  = (int2*)alloc(512*8);
  int*   rowsl  = (int*)alloc(24576ULL*4);
  float* wrowl  = (float*)alloc(24576ULL*4);

  size_t region = off;
  size_t oA = region, oF = region;
  auto allocV = [&](size_t b, size_t& o2)->char*{
    char* p = base + o2; o2 = (o2 + b + 255) & ~(size_t)255; return p;
  };
  // attention view
  float* qkv    = (float*)allocV(6291456ULL*4, oA);
  unsigned short* qkv_hi = (unsigned short*)allocV(6291456ULL*2, oA);
  unsigned short* qkv_lo = (unsigned short*)allocV(6291456ULL*2, oA);
  unsigned short* vT_hi  = (unsigned short*)allocV(2097152ULL*2, oA);
  unsigned short* vT_lo  = (unsigned short*)allocV(2097152ULL*2, oA);
  float* scores = (float*)allocV(8388608ULL*4, oA);
  unsigned short* p_hi = (unsigned short*)allocV(16777216ULL*2, oA);
  unsigned short* p_lo = (unsigned short*)allocV(16777216ULL*2, oA);
  float* attno = (float*)allocV(2097152ULL*4, oA);
  unsigned short* attno_hi = (unsigned short*)allocV(2097152ULL*2, oA);
  unsigned short* attno_lo = (unsigned short*)allocV(2097152ULL*2, oA);
  float* attnw = (float*)allocV(2097152ULL*4, oA);
  // FFN view
  unsigned short* wguT = (unsigned short*)allocV(100663296ULL*2, oF);
  unsigned short* sguT = (unsigned short*)allocV(3145728ULL*2, oF);
  unsigned short* xg   = (unsigned short*)allocV(12582912ULL*2, oF);
  unsigned short* hact = (unsigned short*)allocV(37748736ULL*2, oF);
  unsigned short* shact= (unsigned short*)allocV(12582912ULL*2, oF);
  float* dout  = (float*)allocV(12582912ULL*4, oF);
  float* sdout = (float*)allocV(4194304ULL*4, oF);
  unsigned short* wdT  = wguT;
  unsigned short* swdT = wguT + 50331648ULL;

  hipMemsetAsync(cnt, 0, 768, stream);

  ksplit<<<2048, 256, 0, stream>>>(x, x_hi, x_lo, 524288);
  kTsplit<<<dim3(24,8), 256, 0, stream>>>(w_qkv, wqkvT_hi, wqkvT_lo, 512, 1536);
  kTsplit<<<dim3(8,8),  256, 0, stream>>>(w_o, woT_hi, woT_lo, 512, 512);
  kTsplit<<<dim3(1,8),  256, 0, stream>>>(router_w, wrT_hi, wrT_lo, 512, 64);

  gemm_x3<2,2,4,4><<<dim3(32,12,1), 256, 0, stream>>>(x_hi, x_lo, wqkvT_hi, wqkvT_lo,
      qkv, 512, 512, 512, 1536, 1.0f, 0,0,1, 0,0,1, 0,0,1);
  krope<<<4096, 256, 0, stream>>>(qkv, qkv_hi, qkv_lo, cosb, sinb);
  kvtrans<<<dim3(16,32), 256, 0, stream>>>(qkv, vT_hi, vT_lo);

  for (int bp = 0; bp < 2; bp++){
    for (int lb = 0; lb < 2; lb++){
      int b = bp*2 + lb;
      const unsigned short* qa = qkv_hi + (size_t)b*1572864;
      const unsigned short* ql = qkv_lo + (size_t)b*1572864;
      gemm_x3<2,2,4,4><<<dim3(8,8,8), 256, 0, stream>>>(qa, ql, qa+512, ql+512,
          scores, 64, 1536, 1536, 1024, 0.125f, 0,64,8, 0,64,8, 0,1048576LL,8);
      ksoftmax<<<8192, 256, 0, stream>>>(scores,
          p_hi + (size_t)lb*8388608, p_lo + (size_t)lb*8388608);
    }
    gemm_x3<2,2,2,2><<<dim3(16,1,16), 256, 0, stream>>>(p_hi, p_lo,
        vT_hi + (size_t)bp*1048576, vT_lo + (size_t)bp*1048576,
        attno + (size_t)bp*1048576, 1024, 1024, 1024, 512, 1.0f,
        1048576LL,0,1, 65536LL,0,1, 524288LL,64,8);
  }
  ksplit<<<2048, 256, 0, stream>>>(attno, attno_hi, attno_lo, 524288);
  gemm_x3<2,2,4,4><<<dim3(32,4,1), 256, 0, stream>>>(attno_hi, attno_lo, woT_hi, woT_lo,
      attnw, 512, 512, 512, 512, 1.0f, 0,0,1, 0,0,1, 0,0,1);
  krms1<<<4096, 128, 0, stream>>>(x, attnw, h1_hi, h1_lo, h1b, hbuf);
  gemm_x3<2,2,2,2><<<dim3(64,1,1), 256, 0, stream>>>(h1_hi, h1_lo, wrT_hi, wrT_lo,
      logits, 512, 512, 512, 64, 1.0f, 0,0,1, 0,0,1, 0,0,1);
  krouter<<<1024, 256, 0, stream>>>(logits, probs, idx, wts, flagcnt, flaglist);
  kfix_attn<<<dim3(1024,8), 256, 0, stream>>>(flagcnt, flaglist, qkv, fixo);
  kfix_route<<<1024, 256, 0, stream>>>(flagcnt, flaglist, fixo, x, w_o, router_w, idx, wts, probs);
  kcount<<<96, 256, 0, stream>>>(idx, cnt);
  ksump<<<64, 256, 0, stream>>>(probs, sumP);
  kfinalize<<<1, 64, 0, stream>>>(cnt, offs, tiles, ntl);
  kscatter<<<96, 256, 0, stream>>>(idx, wts, offs, cursor, rowsl, wrowl, slot_of);

  // ---- FFN phase ----
  kgather<<<6144, 256, 0, stream>>>(h1b, rowsl, xg);
  kconvT<true><<<dim3(48,8,64), 256, 0, stream>>>(r_wgu, wguT, 512, 3072);
  kconvT<true><<<dim3(48,8,2),  256, 0, stream>>>(s_wgu, sguT, 512, 3072);
  gemm_ffn<0><<<6144, 256, 0, stream>>>(xg, wguT, hact, nullptr, offs, tiles, ntl, 3072, 512);
  gemm_ffn<2><<<dim3(32,24,2), 256, 0, stream>>>(h1b, sguT, shact, nullptr, offs, tiles, ntl, 3072, 512);
  kconvT<false><<<dim3(8,24,64), 256, 0, stream>>>(r_wd, wdT, 1536, 512);
  kconvT<false><<<dim3(8,24,2),  256, 0, stream>>>(s_wd, swdT, 1536, 512);
  gemm_ffn<1><<<1024, 256, 0, stream>>>(hact, wdT, nullptr, dout, offs, tiles, ntl, 512, 1536);
  gemm_ffn<3><<<dim3(32,4,2), 256, 0, stream>>>(shact, swdT, nullptr, sdout, offs, tiles, ntl, 512, 1536);

  kreduce<<<4096, 128, 0, stream>>>(hbuf, sdout, dout, slot_of, wts, out);
  kscalars<<<1, 64, 0, stream>>>(cnt, sumP, out + 2097152);
}

// Round 6
// 1378.628 us; speedup vs baseline: 1.0168x; 1.0168x over previous
//
// Round 6: global_load_lds staging in FFN GEMMs (m97 pattern), batched single-launch
// attention (scores/softmax/PV z=32), PV epilogue split-fusion, wave-parallel kfinalize.
#include <hip/hip_runtime.h>
#include <math.h>

#define TOK   4096
#define SEQL  1024
#define HID   512
#define NEXP  64
#define FFI   1536

typedef short bf16x8v __attribute__((ext_vector_type(8)));
typedef float f32x4   __attribute__((ext_vector_type(4)));

__device__ __forceinline__ unsigned short f2bf(float f){
  unsigned int u = __float_as_uint(f);
  u += 0x7fffu + ((u >> 16) & 1u);
  return (unsigned short)(u >> 16);
}
__device__ __forceinline__ float bf2f(unsigned short s){
  return __uint_as_float(((unsigned int)s) << 16);
}
__device__ __forceinline__ void split2(float v, unsigned short& h, unsigned short& l){
  h = f2bf(v);
  l = f2bf(v - bf2f(h));
}
// async global->LDS, 16B per lane; LDS dest is wave-uniform base + lane*16
__device__ __forceinline__ void gload16(const void* g, void* l){
  __builtin_amdgcn_global_load_lds(
      (const __attribute__((address_space(1))) unsigned int*)g,
      (__attribute__((address_space(3))) unsigned int*)l, 16, 0, 0);
}
// bijective chunked XCD swizzle over [0,total)
__device__ __forceinline__ int xcd_swizzle(int raw, int total){
  int q = total >> 3, r = total & 7;
  int xcd = raw & 7, pos = raw >> 3;
  int csz = (xcd < r) ? (q + 1) : q;
  if (pos >= csz) return -1;
  int basel = (xcd < r) ? xcd * (q + 1) : r * (q + 1) + (xcd - r) * q;
  return basel + pos;
}

// ---------------- elementwise split fp32 -> hi/lo bf16 ----------------
__global__ __launch_bounds__(256) void ksplit(const float* __restrict__ in,
    unsigned short* __restrict__ hi, unsigned short* __restrict__ lo, int n4){
  int g = blockIdx.x*256 + threadIdx.x;
  if (g >= n4) return;
  float4 v = *(const float4*)&in[(long long)g*4];
  unsigned short h0,h1,h2,h3,l0,l1,l2,l3;
  split2(v.x,h0,l0); split2(v.y,h1,l1); split2(v.z,h2,l2); split2(v.w,h3,l3);
  *(ushort4*)&hi[(long long)g*4] = make_ushort4(h0,h1,h2,h3);
  *(ushort4*)&lo[(long long)g*4] = make_ushort4(l0,l1,l2,l3);
}

// ---------------- transpose + split: fp32 [R][C] -> hi/lo bf16 [C][R] ----------------
__global__ __launch_bounds__(256) void kTsplit(const float* __restrict__ in,
    unsigned short* __restrict__ ohi, unsigned short* __restrict__ olo, int R, int C){
  __shared__ float tile[64][65];
  int c0 = blockIdx.x*64, r0 = blockIdx.y*64;
  int tid = threadIdx.x;
  #pragma unroll
  for (int it=0; it<4; it++){
    int idx = it*256+tid; int r = idx>>4; int cq = (idx&15)*4;
    float4 v = *(const float4*)&in[(long long)(r0+r)*C + c0 + cq];
    tile[r][cq]=v.x; tile[r][cq+1]=v.y; tile[r][cq+2]=v.z; tile[r][cq+3]=v.w;
  }
  __syncthreads();
  #pragma unroll
  for (int it=0; it<2; it++){
    int idx = it*256+tid; int c = idx>>3; int rq=(idx&7)*8;
    unsigned short th[8] __attribute__((aligned(16)));
    unsigned short tl[8] __attribute__((aligned(16)));
    #pragma unroll
    for (int j=0;j<8;j++) split2(tile[rq+j][c], th[j], tl[j]);
    long long o = (long long)(c0+c)*R + r0 + rq;
    *(uint4*)&ohi[o] = *(uint4*)th;
    *(uint4*)&olo[o] = *(uint4*)tl;
  }
}

// -------- weight convert+transpose fp32 [Z][R][C] -> bf16 [Z][C][R]; optional gate/up pairing --------
template<bool PAIRED>
__global__ __launch_bounds__(256) void kconvT(const float* __restrict__ in,
    unsigned short* __restrict__ out, int R, int C){
  __shared__ float tile[64][65];
  long long zb = (long long)blockIdx.z * R * C;
  int c0 = blockIdx.x*64, r0 = blockIdx.y*64;
  int tid = threadIdx.x;
  #pragma unroll
  for (int it=0; it<4; it++){
    int idx = it*256+tid; int r = idx>>4; int cq = (idx&15)*4;
    float4 v = *(const float4*)&in[zb + (long long)(r0+r)*C + c0 + cq];
    tile[r][cq]=v.x; tile[r][cq+1]=v.y; tile[r][cq+2]=v.z; tile[r][cq+3]=v.w;
  }
  __syncthreads();
  #pragma unroll
  for (int it=0; it<2; it++){
    int idx = it*256+tid; int c = idx>>3; int rq=(idx&7)*8;
    unsigned short tb[8] __attribute__((aligned(16)));
    #pragma unroll
    for (int j=0;j<8;j++) tb[j] = f2bf(tile[rq+j][c]);
    int cc = c0 + c;
    int orow = PAIRED ? ((cc < (C>>1)) ? 2*cc : 2*(cc-(C>>1))+1) : cc;
    *(uint4*)&out[zb + (long long)orow*R + r0 + rq] = *(uint4*)tb;
  }
}

// ---------------- bf16x3 TN GEMM: C = alpha * (Ahi+Alo)(Bhi+Blo)^T (drop lo*lo) ----------------
// SPLIT=0: write float C.  SPLIT=1: write hi/lo bf16 (OH/OL).
template<int WM,int WN,int FM,int FN,int SPLIT>
__global__ __launch_bounds__(256) void gemm_x3(
    const unsigned short* __restrict__ Ahi, const unsigned short* __restrict__ Alo,
    const unsigned short* __restrict__ Bhi, const unsigned short* __restrict__ Blo,
    float* __restrict__ C, unsigned short* __restrict__ OH, unsigned short* __restrict__ OL,
    int K, int lda, int ldb, int ldc, float alpha,
    long long a1, long long a2, int adiv,
    long long b1, long long b2, int bdiv,
    long long c1, long long c2, int cdiv)
{
  constexpr int BM = WM*FM*16, BN = WN*FN*16;
  constexpr int AIT = (2*BM*4)/256, BIT = (2*BN*4)/256;
  int z = blockIdx.z;
  long long aoff = (long long)(z/adiv)*a1 + (long long)(z%adiv)*a2;
  long long boff = (long long)(z/bdiv)*b1 + (long long)(z%bdiv)*b2;
  long long coff = (long long)(z/cdiv)*c1 + (long long)(z%cdiv)*c2;
  int m0 = blockIdx.x*BM, n0 = blockIdx.y*BN;
  __shared__ __align__(16) unsigned short As[2][BM*40];
  __shared__ __align__(16) unsigned short Bs[2][BN*40];
  int tid = threadIdx.x, lane = tid&63, wid = tid>>6;
  int wr = wid / WN, wc = wid % WN;
  int lrow = lane&15, kgo = (lane>>4)*8;
  f32x4 acc[FM][FN];
  #pragma unroll
  for (int mi=0;mi<FM;mi++)
    #pragma unroll
    for (int nj=0;nj<FN;nj++) acc[mi][nj] = (f32x4){0.f,0.f,0.f,0.f};

  for (int k0=0; k0<K; k0+=32){
    uint4 ta[AIT], tb[BIT];
    #pragma unroll
    for (int it=0; it<AIT; it++){
      int c = it*256+tid; int pl = c/(BM*4); int rem = c%(BM*4);
      int row = rem>>2, q = (rem&3)*8;
      const unsigned short* src = pl ? Alo : Ahi;
      ta[it] = *(const uint4*)&src[aoff + (long long)(m0+row)*lda + k0 + q];
    }
    #pragma unroll
    for (int it=0; it<BIT; it++){
      int c = it*256+tid; int pl = c/(BN*4); int rem = c%(BN*4);
      int row = rem>>2, q = (rem&3)*8;
      const unsigned short* src = pl ? Blo : Bhi;
      tb[it] = *(const uint4*)&src[boff + (long long)(n0+row)*ldb + k0 + q];
    }
    __syncthreads();
    #pragma unroll
    for (int it=0; it<AIT; it++){
      int c = it*256+tid; int pl = c/(BM*4); int rem = c%(BM*4);
      int row = rem>>2, q = (rem&3)*8;
      *(uint4*)&As[pl][row*40+q] = ta[it];
    }
    #pragma unroll
    for (int it=0; it<BIT; it++){
      int c = it*256+tid; int pl = c/(BN*4); int rem = c%(BN*4);
      int row = rem>>2, q = (rem&3)*8;
      *(uint4*)&Bs[pl][row*40+q] = tb[it];
    }
    __syncthreads();
    bf16x8v ah[FM], al[FM], bh[FN], bl[FN];
    int ab = (wr*FM*16 + lrow)*40 + kgo;
    int bb = (wc*FN*16 + lrow)*40 + kgo;
    #pragma unroll
    for (int mi=0;mi<FM;mi++){
      ah[mi] = *(const bf16x8v*)&As[0][ab + mi*640];
      al[mi] = *(const bf16x8v*)&As[1][ab + mi*640];
    }
    #pragma unroll
    for (int nj=0;nj<FN;nj++){
      bh[nj] = *(const bf16x8v*)&Bs[0][bb + nj*640];
      bl[nj] = *(const bf16x8v*)&Bs[1][bb + nj*640];
    }
    #pragma unroll
    for (int mi=0;mi<FM;mi++)
      #pragma unroll
      for (int nj=0;nj<FN;nj++){
        acc[mi][nj] = __builtin_amdgcn_mfma_f32_16x16x32_bf16(ah[mi], bh[nj], acc[mi][nj], 0,0,0);
        acc[mi][nj] = __builtin_amdgcn_mfma_f32_16x16x32_bf16(ah[mi], bl[nj], acc[mi][nj], 0,0,0);
        acc[mi][nj] = __builtin_amdgcn_mfma_f32_16x16x32_bf16(al[mi], bh[nj], acc[mi][nj], 0,0,0);
      }
  }
  int crow = m0 + wr*FM*16 + ((lane>>4)<<2);
  int ccol = n0 + wc*FN*16 + (lane&15);
  #pragma unroll
  for (int mi=0;mi<FM;mi++)
    #pragma unroll
    for (int r=0;r<4;r++){
      long long row = crow + mi*16 + r;
      #pragma unroll
      for (int nj=0;nj<FN;nj++){
        float v = alpha*acc[mi][nj][r];
        if constexpr (SPLIT){
          unsigned short hh, ll;
          split2(v, hh, ll);
          OH[coff + row*ldc + ccol + nj*16] = hh;
          OL[coff + row*ldc + ccol + nj*16] = ll;
        } else {
          C[coff + row*ldc + ccol + nj*16] = v;
        }
      }
    }
}

// ---------------- RoPE: rotate q,k in fp32 (write back) + split to hi/lo ----------------
__global__ __launch_bounds__(256) void krope(float* __restrict__ qkv,
    unsigned short* __restrict__ qhi, unsigned short* __restrict__ qlo,
    const float* __restrict__ cosb, const float* __restrict__ sinb){
  int gid = blockIdx.x*256 + threadIdx.x;
  int t = gid >> 8; int rem = gid & 255; int h = rem >> 5; int d = rem & 31;
  int s = t & (SEQL-1);
  long long base = (long long)t*1536 + h*64;
  float c1 = cosb[s*64+d], c2 = cosb[s*64+d+32];
  float s1 = sinb[s*64+d], s2 = sinb[s*64+d+32];
  float q1 = qkv[base+d], q2 = qkv[base+d+32];
  float rq1 = q1*c1 - q2*s1, rq2 = q2*c2 + q1*s2;
  qkv[base+d] = rq1; qkv[base+d+32] = rq2;
  split2(rq1, qhi[base+d],    qlo[base+d]);
  split2(rq2, qhi[base+d+32], qlo[base+d+32]);
  float k1 = qkv[base+512+d], k2 = qkv[base+512+d+32];
  float rk1 = k1*c1 - k2*s1, rk2 = k2*c2 + k1*s2;
  qkv[base+512+d] = rk1; qkv[base+512+d+32] = rk2;
  split2(rk1, qhi[base+512+d],    qlo[base+512+d]);
  split2(rk2, qhi[base+512+d+32], qlo[base+512+d+32]);
}

// ---------------- V transpose ----------------
__global__ __launch_bounds__(256) void kvtrans(const float* __restrict__ qkv,
    unsigned short* __restrict__ vhi, unsigned short* __restrict__ vlo){
  __shared__ float tile[64][65];
  int s0 = blockIdx.x*64;
  int z = blockIdx.y;
  int b = z >> 3, h = z & 7;
  int tid = threadIdx.x;
  #pragma unroll
  for (int it=0; it<4; it++){
    int idx = it*256+tid; int r = idx>>4; int cq = (idx&15)*4;
    float4 v = *(const float4*)&qkv[((long long)(b*1024 + s0 + r))*1536 + 1024 + h*64 + cq];
    tile[r][cq]=v.x; tile[r][cq+1]=v.y; tile[r][cq+2]=v.z; tile[r][cq+3]=v.w;
  }
  __syncthreads();
  #pragma unroll
  for (int it=0; it<2; it++){
    int idx = it*256+tid; int d = idx>>3; int sq = (idx&7)*8;
    unsigned short th[8] __attribute__((aligned(16)));
    unsigned short tl[8] __attribute__((aligned(16)));
    #pragma unroll
    for (int j=0;j<8;j++) split2(tile[sq+j][d], th[j], tl[j]);
    long long o = ((long long)(z*64 + d))*1024 + s0 + sq;
    *(uint4*)&vhi[o] = *(uint4*)th;
    *(uint4*)&vlo[o] = *(uint4*)tl;
  }
}

// ---------------- softmax rows of 1024, output split bf16 ----------------
__global__ __launch_bounds__(256) void ksoftmax(const float* __restrict__ sc,
    unsigned short* __restrict__ phi, unsigned short* __restrict__ plo){
  long long row = blockIdx.x;
  const float* p = sc + row*1024;
  int tid = threadIdx.x;
  float4 v = *(const float4*)&p[tid*4];
  float m = fmaxf(fmaxf(v.x,v.y), fmaxf(v.z,v.w));
  for (int o=32;o>0;o>>=1) m = fmaxf(m, __shfl_xor(m,o));
  __shared__ float redm[4], reds[4];
  int wid = tid>>6, lane = tid&63;
  if (lane==0) redm[wid]=m;
  __syncthreads();
  m = fmaxf(fmaxf(redm[0],redm[1]), fmaxf(redm[2],redm[3]));
  float e0=expf(v.x-m), e1=expf(v.y-m), e2=expf(v.z-m), e3=expf(v.w-m);
  float sum = e0+e1+e2+e3;
  for (int o=32;o>0;o>>=1) sum += __shfl_xor(sum,o);
  if (lane==0) reds[wid]=sum;
  __syncthreads();
  sum = reds[0]+reds[1]+reds[2]+reds[3];
  float inv = 1.0f/sum;
  unsigned short h0,h1,h2,h3,l0,l1,l2,l3;
  split2(e0*inv,h0,l0); split2(e1*inv,h1,l1); split2(e2*inv,h2,l2); split2(e3*inv,h3,l3);
  *(ushort4*)&phi[row*1024 + tid*4] = make_ushort4(h0,h1,h2,h3);
  *(ushort4*)&plo[row*1024 + tid*4] = make_ushort4(l0,l1,l2,l3);
}

// ---------------- rms_norm(x+attn) -> h1 hi/lo + h1b + hbuf(f32) ----------------
__global__ __launch_bounds__(128) void krms1(const float* __restrict__ x, const float* __restrict__ attn,
    unsigned short* __restrict__ h1hi, unsigned short* __restrict__ h1lo,
    unsigned short* __restrict__ h1b, float* __restrict__ hbuf){
  long long row = blockIdx.x;
  int tid = threadIdx.x;
  float4 xv = *(const float4*)&x[row*512 + tid*4];
  float4 av = *(const float4*)&attn[row*512 + tid*4];
  float4 v; v.x=xv.x+av.x; v.y=xv.y+av.y; v.z=xv.z+av.z; v.w=xv.w+av.w;
  float ss = v.x*v.x + v.y*v.y + v.z*v.z + v.w*v.w;
  for (int o=32;o>0;o>>=1) ss += __shfl_xor(ss,o);
  __shared__ float red[2];
  int wid = tid>>6, lane = tid&63;
  if (lane==0) red[wid]=ss;
  __syncthreads();
  ss = red[0]+red[1];
  float r = 1.0f/sqrtf(ss*(1.0f/512.0f) + 1e-5f);
  float4 o; o.x=v.x*r; o.y=v.y*r; o.z=v.z*r; o.w=v.w*r;
  *(float4*)&hbuf[row*512 + tid*4] = o;
  unsigned short h0,h1,h2,h3,l0,l1,l2,l3;
  split2(o.x,h0,l0); split2(o.y,h1,l1); split2(o.z,h2,l2); split2(o.w,h3,l3);
  *(ushort4*)&h1hi[row*512 + tid*4] = make_ushort4(h0,h1,h2,h3);
  *(ushort4*)&h1lo[row*512 + tid*4] = make_ushort4(l0,l1,l2,l3);
  *(ushort4*)&h1b[row*512 + tid*4] = make_ushort4(f2bf(o.x),f2bf(o.y),f2bf(o.z),f2bf(o.w));
}

// ---------------- routing decision (one 64-lane wave per token) ----------------
__device__ void route_decide(float p, int e, int t,
    int* __restrict__ idx, float* __restrict__ wts,
    int* __restrict__ flagcnt, int* __restrict__ flaglist){
  float d = p;
  d += __shfl_xor(d,1); d += __shfl_xor(d,2); d += __shfl_xor(d,4);
  int g = e >> 3;
  float gs[8];
  #pragma unroll
  for (int j=0;j<8;j++) gs[j] = __shfl(d, j*8);
  int rank = 0;
  #pragma unroll
  for (int j=0;j<8;j++) rank += (gs[j] > d) || (gs[j] == d && j < g);
  float q = (rank < 3) ? p : -INFINITY;
  float svals[7]; int sidx[7];
  #pragma unroll
  for (int kk=0; kk<7; kk++){
    float v = q; int vi = e;
    for (int o=32;o>0;o>>=1){
      float ov = __shfl_xor(v,o); int oi = __shfl_xor(vi,o);
      if (ov > v || (ov == v && oi < vi)){ v = ov; vi = oi; }
    }
    svals[kk] = v; sidx[kk] = vi;
    if (e == vi) q = -INFINITY;
  }
  float mx = svals[0], tot = 0.f, wv[6];
  #pragma unroll
  for (int kk=0;kk<6;kk++){ wv[kk] = expf(svals[kk]-mx); tot += wv[kk]; }
  if (e < 6){
    idx[t*6+e] = sidx[e];
    wts[t*6+e] = wv[e]/tot;
  }
  if (flagcnt != nullptr && e == 0){
    float a[8];
    #pragma unroll
    for (int j=0;j<8;j++) a[j] = gs[j];
    float t3=-1e30f, t4=-1e30f;
    for (int it2=0; it2<4; it2++){
      int bi=0; float bv=a[0];
      #pragma unroll
      for (int j=1;j<8;j++) if (a[j] > bv){ bv=a[j]; bi=j; }
      if (it2==2) t3=bv;
      if (it2==3) t4=bv;
      a[bi] = -1e30f;
    }
    float pgap = svals[5] - svals[6];
    float dgap = t3 - t4;
    if (pgap < 1e-4f || dgap < 5e-4f){
      int pos = atomicAdd(flagcnt, 1);
      if (pos < 1024) flaglist[pos] = t;
    }
  }
}

__global__ __launch_bounds__(256) void krouter(const float* __restrict__ logits,
    float* __restrict__ probs, int* __restrict__ idx, float* __restrict__ wts,
    int* __restrict__ flagcnt, int* __restrict__ flaglist){
  int t = blockIdx.x*4 + (threadIdx.x >> 6);
  int e = threadIdx.x & 63;
  float l = logits[t*64 + e];
  float m = l;
  for (int o=32;o>0;o>>=1) m = fmaxf(m, __shfl_xor(m,o));
  float p = expf(l-m);
  float s = p;
  for (int o=32;o>0;o>>=1) s += __shfl_xor(s,o);
  p /= s;
  probs[t*64+e] = p;
  route_decide(p, e, t, idx, wts, flagcnt, flaglist);
}

// ---------------- exact fp32 attention recompute, one block per (flag, head) ----------------
__global__ __launch_bounds__(256) void kfix_attn(const int* __restrict__ flagcnt,
    const int* __restrict__ flaglist, const float* __restrict__ qkv, float* __restrict__ fixo){
  int fc = *flagcnt; if (fc > 1024) fc = 1024;
  if ((int)blockIdx.x >= fc) return;
  int t = flaglist[blockIdx.x];
  int h = blockIdx.y;
  int b = t >> 10;
  int tid = threadIdx.x, lane = tid & 63, w = tid >> 6;
  __shared__ float sc[1024];
  __shared__ float qh[64];
  __shared__ float red[4];
  __shared__ float op[4][64];
  __shared__ float sinv;
  if (tid < 64) qh[tid] = qkv[(long long)t*1536 + h*64 + tid];
  __syncthreads();
  float q = qh[lane];
  const float* kb = qkv + (long long)b*1024*1536 + 512 + h*64 + lane;
  for (int s0 = w*256; s0 < w*256 + 256; s0 += 8){
    float p[8];
    #pragma unroll
    for (int j=0;j<8;j++) p[j] = q * kb[(long long)(s0+j)*1536];
    #pragma unroll
    for (int o=32;o>0;o>>=1){
      #pragma unroll
      for (int j=0;j<8;j++) p[j] += __shfl_xor(p[j],o);
    }
    if (lane == 0){
      #pragma unroll
      for (int j=0;j<8;j++) sc[s0+j] = p[j] * 0.125f;
    }
  }
  __syncthreads();
  float m = -1e30f;
  for (int s = tid; s < 1024; s += 256) m = fmaxf(m, sc[s]);
  #pragma unroll
  for (int o=32;o>0;o>>=1) m = fmaxf(m, __shfl_xor(m,o));
  if (lane == 0) red[w] = m;
  __syncthreads();
  m = fmaxf(fmaxf(red[0],red[1]), fmaxf(red[2],red[3]));
  __syncthreads();
  float sum = 0.f;
  for (int s = tid; s < 1024; s += 256){ float e = expf(sc[s]-m); sc[s] = e; sum += e; }
  #pragma unroll
  for (int o=32;o>0;o>>=1) sum += __shfl_xor(sum,o);
  if (lane == 0) red[w] = sum;
  __syncthreads();
  if (tid == 0) sinv = 1.0f/(red[0]+red[1]+red[2]+red[3]);
  const float* vb = qkv + (long long)b*1024*1536 + 1024 + h*64 + lane;
  float a0 = 0.f, a1 = 0.f, a2 = 0.f, a3 = 0.f;
  for (int s = w*256; s < w*256 + 256; s += 4){
    a0 += sc[s]   * vb[(long long)(s)*1536];
    a1 += sc[s+1] * vb[(long long)(s+1)*1536];
    a2 += sc[s+2] * vb[(long long)(s+2)*1536];
    a3 += sc[s+3] * vb[(long long)(s+3)*1536];
  }
  op[w][lane] = (a0+a1)+(a2+a3);
  __syncthreads();
  if (tid < 64)
    fixo[(long long)blockIdx.x*512 + h*64 + tid] =
      (op[0][tid]+op[1][tid]+op[2][tid]+op[3][tid]) * sinv;
}

// ---------------- exact fp32 w_o + rms + router for flagged tokens ----------------
__global__ __launch_bounds__(256) void kfix_route(const int* __restrict__ flagcnt,
    const int* __restrict__ flaglist, const float* __restrict__ fixo,
    const float* __restrict__ x, const float* __restrict__ w_o, const float* __restrict__ router_w,
    int* __restrict__ idx, float* __restrict__ wts, float* __restrict__ probs){
  int fc = *flagcnt; if (fc > 1024) fc = 1024;
  if ((int)blockIdx.x >= fc) return;
  int t = flaglist[blockIdx.x];
  int tid = threadIdx.x;
  __shared__ float o512[512];
  __shared__ float h1s[512];
  __shared__ float red[4];
  o512[tid]     = fixo[(long long)blockIdx.x*512 + tid];
  o512[tid+256] = fixo[(long long)blockIdx.x*512 + tid + 256];
  __syncthreads();
  int j0 = tid, j1 = tid + 256;
  float a0 = 0.f, a1 = 0.f;
  #pragma unroll 4
  for (int i = 0; i < 512; i++){
    float oi = o512[i];
    a0 += oi * w_o[(long long)i*512 + j0];
    a1 += oi * w_o[(long long)i*512 + j1];
  }
  float hj0 = x[(long long)t*512 + j0] + a0;
  float hj1 = x[(long long)t*512 + j1] + a1;
  float ss = hj0*hj0 + hj1*hj1;
  #pragma unroll
  for (int o=32;o>0;o>>=1) ss += __shfl_xor(ss,o);
  if ((tid&63)==0) red[tid>>6]=ss;
  __syncthreads();
  ss = red[0]+red[1]+red[2]+red[3];
  float r = 1.0f/sqrtf(ss*(1.0f/512.0f) + 1e-5f);
  h1s[j0] = hj0*r; h1s[j1] = hj1*r;
  __syncthreads();
  if (tid < 64){
    int e = tid;
    float le = 0.f;
    #pragma unroll 4
    for (int i=0;i<512;i++) le += h1s[i]*router_w[(long long)i*64 + e];
    float m2 = le;
    #pragma unroll
    for (int o=32;o>0;o>>=1) m2 = fmaxf(m2, __shfl_xor(m2,o));
    float p = expf(le - m2), s2 = p;
    #pragma unroll
    for (int o=32;o>0;o>>=1) s2 += __shfl_xor(s2,o);
    p /= s2;
    probs[(long long)t*64 + e] = p;
    route_decide(p, e, t, idx, wts, nullptr, nullptr);
  }
}

__global__ void kcount(const int* __restrict__ idx, int* __restrict__ cnt){
  int g = blockIdx.x*256 + threadIdx.x;
  if (g < TOK*6) atomicAdd(&cnt[idx[g]], 1);
}

__global__ __launch_bounds__(256) void ksump(const float* __restrict__ probs, float* __restrict__ sumP){
  int e = blockIdx.x; int tid = threadIdx.x;
  float acc = 0.f;
  for (int t = tid; t < TOK; t += 256) acc += probs[t*64 + e];
  for (int o=32;o>0;o>>=1) acc += __shfl_xor(acc,o);
  __shared__ float red[4];
  int wid = tid>>6, lane = tid&63;
  if (lane==0) red[wid]=acc;
  __syncthreads();
  if (tid==0) sumP[e] = red[0]+red[1]+red[2]+red[3];
}

// wave-parallel: prefix sums over 64 experts (one wave)
__global__ void kfinalize(const int* __restrict__ cnt, int* __restrict__ offs,
                          int2* __restrict__ tiles, int* __restrict__ ntl){
  int e = threadIdx.x;     // 64 threads
  int c = cnt[e];
  int inc = c;
  #pragma unroll
  for (int o=1;o<64;o<<=1){ int v = __shfl_up(inc,o); if (e>=o) inc += v; }
  offs[e] = inc - c;
  if (e == 63) offs[64] = inc;
  int nte = (c + 127) >> 7;
  int tinc = nte;
  #pragma unroll
  for (int o=1;o<64;o<<=1){ int v = __shfl_up(tinc,o); if (e>=o) tinc += v; }
  int tbase = tinc - nte;
  for (int i=0;i<nte;i++) tiles[tbase+i] = make_int2(e, i*128);
  if (e == 63) *ntl = tinc;
}

__global__ __launch_bounds__(256) void kscatter(const int* __restrict__ idx, const float* __restrict__ wts,
    const int* __restrict__ offs, int* __restrict__ cursor,
    int* __restrict__ rowsl, float* __restrict__ wrowl, int* __restrict__ slot_of){
  int g = blockIdx.x*256 + threadIdx.x;
  if (g >= TOK*6) return;
  int t = g/6, kk = g%6;
  int e = idx[t*6+kk];
  int pos = atomicAdd(&cursor[e], 1);
  int slot = offs[e]+pos;
  rowsl[slot] = t;
  wrowl[slot] = wts[t*6+kk];
  slot_of[t*6+kk] = slot;
}

__global__ __launch_bounds__(256) void kgather(const unsigned short* __restrict__ h1b,
    const int* __restrict__ rowsl, unsigned short* __restrict__ xg){
  int r = blockIdx.x*4 + (threadIdx.x>>6);
  int lane = threadIdx.x&63;
  int tok = rowsl[r];
  *(uint4*)&xg[(long long)r*512 + lane*8] = *(const uint4*)&h1b[(long long)tok*512 + lane*8];
}

// ---------------- FFN bf16 MFMA GEMM (128x128, BK=32) with global_load_lds staging ----------------
// MODE 0: expert gate/up (A=xg) + fused SwiGLU -> hact [paired weights]
// MODE 1: expert down (A=hact) -> dense f32 dout
// MODE 2: shared gate/up (A=h1b) + fused SwiGLU -> shact
// MODE 3: shared down (A=shact) -> dense f32 sdout
template<int MODE>
__global__ __launch_bounds__(256) void gemm_ffn(
    const unsigned short* __restrict__ Ab, const unsigned short* __restrict__ Bw,
    unsigned short* __restrict__ Cact, float* __restrict__ Cd,
    const int* __restrict__ offs, const int2* __restrict__ tiles, const int* __restrict__ ntl,
    int N, int K)
{
  int e=0, m0=0, roff=0, Me=1<<30, n0=0, zi=0;
  long long Aoff=0, Boff=0;
  int lda;
  if constexpr (MODE==0 || MODE==1){
    constexpr int NF = (MODE==0) ? 24 : 4;
    int nt = *ntl;
    int total = nt*NF;
    int l = xcd_swizzle(blockIdx.x, total);
    if (l < 0 || l >= total) return;
    int tile = l / NF; int y = l % NF;
    int2 tl = tiles[tile];
    e = tl.x; m0 = tl.y;
    roff = offs[e]; Me = offs[e+1]-roff;
    n0 = y*128;
    Boff = (long long)e*N*K;
    lda = K;
  } else {
    m0 = blockIdx.x*128;
    n0 = blockIdx.y*128;
    zi = blockIdx.z;
    Boff = (long long)zi*N*K;
    if constexpr (MODE==2) lda = 512;
    else { lda = K; Aoff = (long long)zi*4096LL*K; }
  }
  // linear LDS [128 rows][32 bf16] per buffer (64 B/row) - global_load_lds layout
  __shared__ __align__(16) unsigned short As[128*32];
  __shared__ __align__(16) unsigned short Bs[128*32];
  int tid = threadIdx.x, lane = tid&63, wid = tid>>6;
  int wr = wid>>1, wc = wid&1;
  int lrow = lane&15, kgo = (lane>>4)*8;
  f32x4 acc[4][4];
  #pragma unroll
  for (int mi=0;mi<4;mi++)
    #pragma unroll
    for (int nj=0;nj<4;nj++) acc[mi][nj] = (f32x4){0.f,0.f,0.f,0.f};

  // staging: each wave issues 2 A-groups + 2 B-groups of 16 rows (1 KB) each.
  // lane l covers row g*16 + l/4, cols (l&3)*8 .. +8
  int g0 = wid*2, g1 = wid*2 + 1;
  int colq = (lane&3)*8;
  int ar0 = g0*16 + (lane>>2), ar1 = g1*16 + (lane>>2);
  long long abase0, abase1;
  if constexpr (MODE==0 || MODE==1){
    int r0 = roff + m0 + ar0; if (r0 > 24575) r0 = 24575;
    int r1 = roff + m0 + ar1; if (r1 > 24575) r1 = 24575;
    abase0 = (long long)r0*lda; abase1 = (long long)r1*lda;
  } else if constexpr (MODE==2){
    abase0 = (long long)(m0+ar0)*lda; abase1 = (long long)(m0+ar1)*lda;
  } else {
    abase0 = Aoff + (long long)(m0+ar0)*lda; abase1 = Aoff + (long long)(m0+ar1)*lda;
  }
  long long bbase0 = Boff + (long long)(n0+ar0)*K;
  long long bbase1 = Boff + (long long)(n0+ar1)*K;

  for (int k0=0; k0<K; k0+=32){
    __syncthreads();     // previous compute done before overwrite
    gload16(Ab + abase0 + k0 + colq, &As[g0*512]);
    gload16(Ab + abase1 + k0 + colq, &As[g1*512]);
    gload16(Bw + bbase0 + k0 + colq, &Bs[g0*512]);
    gload16(Bw + bbase1 + k0 + colq, &Bs[g1*512]);
    __syncthreads();     // vmcnt(0) drained by barrier -> data visible
    bf16x8v af[4], bfv[4];
    int ab = (wr*64 + lrow)*32 + kgo;
    int bb = (wc*64 + lrow)*32 + kgo;
    #pragma unroll
    for (int mi=0;mi<4;mi++) af[mi]  = *(const bf16x8v*)&As[ab + mi*512];
    #pragma unroll
    for (int nj=0;nj<4;nj++) bfv[nj] = *(const bf16x8v*)&Bs[bb + nj*512];
    #pragma unroll
    for (int mi=0;mi<4;mi++)
      #pragma unroll
      for (int nj=0;nj<4;nj++)
        acc[mi][nj] = __builtin_amdgcn_mfma_f32_16x16x32_bf16(af[mi], bfv[nj], acc[mi][nj], 0,0,0);
  }

  int lq = lane>>4;
  int l15 = lane&15;
  if constexpr (MODE==0 || MODE==2){
    bool evenlane = (l15&1)==0;
    int pb = (n0>>1) + wc*32 + (l15>>1);
    #pragma unroll
    for (int mi=0;mi<4;mi++){
      #pragma unroll
      for (int r2=0;r2<4;r2++){
        int lr = wr*64 + mi*16 + lq*4 + r2;
        bool valid; long long grow;
        if constexpr (MODE==0){ valid = (m0+lr)<Me; grow = roff+m0+lr; }
        else { valid = true; grow = (long long)zi*4096 + m0 + lr; }
        #pragma unroll
        for (int nj=0;nj<4;nj++){
          float v = acc[mi][nj][r2];
          float o2 = __shfl_xor(v,1);
          if (evenlane && valid){
            float g = v, u = o2;
            float sg = g/(1.0f+expf(-g))*u;
            Cact[grow*1536 + pb + nj*8] = f2bf(sg);
          }
        }
      }
    }
  } else {
    #pragma unroll
    for (int mi=0;mi<4;mi++)
      #pragma unroll
      for (int r2=0;r2<4;r2++){
        int lr = wr*64 + mi*16 + lq*4 + r2;
        bool valid; long long grow;
        if constexpr (MODE==1){ valid = (m0+lr)<Me; grow = roff+m0+lr; }
        else { valid = true; grow = (long long)zi*4096 + m0 + lr; }
        if (valid){
          #pragma unroll
          for (int nj=0;nj<4;nj++)
            Cd[grow*512 + n0 + wc*64 + nj*16 + l15] = acc[mi][nj][r2];
        }
      }
  }
}

// ---------------- final reduce: out = rms(h1 + shared + routed) ----------------
__global__ __launch_bounds__(128) void kreduce(const float* __restrict__ hbuf,
    const float* __restrict__ sdout, const float* __restrict__ dout,
    const int* __restrict__ slot_of, const float* __restrict__ wts,
    float* __restrict__ out){
  int t = blockIdx.x;
  int tid = threadIdx.x;
  int c4 = tid*4;
  float4 s = *(const float4*)&hbuf[(long long)t*512 + c4];
  float4 a = *(const float4*)&sdout[(long long)t*512 + c4];
  float4 b = *(const float4*)&sdout[(long long)(4096+t)*512 + c4];
  s.x += a.x + b.x; s.y += a.y + b.y; s.z += a.z + b.z; s.w += a.w + b.w;
  #pragma unroll
  for (int kk=0; kk<6; kk++){
    float w = wts[t*6+kk];
    int slot = slot_of[t*6+kk];
    float4 d = *(const float4*)&dout[(long long)slot*512 + c4];
    s.x += w*d.x; s.y += w*d.y; s.z += w*d.z; s.w += w*d.w;
  }
  float ss = s.x*s.x + s.y*s.y + s.z*s.z + s.w*s.w;
  for (int o=32;o>0;o>>=1) ss += __shfl_xor(ss,o);
  __shared__ float red[2];
  int wid = tid>>6, lane = tid&63;
  if (lane==0) red[wid]=ss;
  __syncthreads();
  ss = red[0]+red[1];
  float r = 1.0f/sqrtf(ss*(1.0f/512.0f) + 1e-5f);
  float4 o; o.x=s.x*r; o.y=s.y*r; o.z=s.z*r; o.w=s.w*r;
  *(float4*)&out[(long long)t*512 + c4] = o;
}

// ---------------- balance-loss scalars ----------------
__global__ void kscalars(const int* __restrict__ cnt, const float* __restrict__ sumP, float* __restrict__ o){
  int e = threadIdx.x;
  float cf = (float)cnt[e];
  float f = cf / 24576.0f;
  float P = sumP[e] / 4096.0f;
  float fg = f, Pg = P, cg = cf;
  fg += __shfl_xor(fg,1); fg += __shfl_xor(fg,2); fg += __shfl_xor(fg,4);
  Pg += __shfl_xor(Pg,1); Pg += __shfl_xor(Pg,2); Pg += __shfl_xor(Pg,4);
  cg += __shfl_xor(cg,1); cg += __shfl_xor(cg,2); cg += __shfl_xor(cg,4);
  float t1 = f*P;
  float t2 = ((e&7)==0) ? (fg/8.0f)*Pg : 0.0f;
  float t3 = ((e&7)==0) ? (cg/12288.0f)*Pg : 0.0f;
  for (int s=32;s>0;s>>=1){
    t1 += __shfl_xor(t1,s); t2 += __shfl_xor(t2,s); t3 += __shfl_xor(t3,s);
  }
  if (e==0){
    float ebl = t1*0.003f, dbl = t2*0.05f, cbl = t3*0.02f;
    o[0]=ebl; o[1]=dbl; o[2]=cbl; o[3]=ebl+dbl+cbl;
  }
}

// ---------------- launch ----------------
extern "C" void kernel_launch(void* const* d_in, const int* in_sizes, int n_in,
                              void* d_out, int out_size, void* d_ws, size_t ws_size,
                              hipStream_t stream){
  const float* x        = (const float*)d_in[0];
  const float* cosb     = (const float*)d_in[1];
  const float* sinb     = (const float*)d_in[2];
  const float* w_qkv    = (const float*)d_in[3];
  const float* w_o      = (const float*)d_in[4];
  const float* router_w = (const float*)d_in[5];
  const float* r_wgu    = (const float*)d_in[6];
  const float* r_wd     = (const float*)d_in[7];
  const float* s_wgu    = (const float*)d_in[8];
  const float* s_wd     = (const float*)d_in[9];
  float* out = (float*)d_out;

  char* base = (char*)d_ws;
  size_t off = 0;
  auto alloc = [&](size_t b)->char*{
    char* p = base + off; off = (off + b + 255) & ~(size_t)255; return p;
  };
  // persistent
  unsigned short* x_hi   = (unsigned short*)alloc(2097152ULL*2);
  unsigned short* x_lo   = (unsigned short*)alloc(2097152ULL*2);
  unsigned short* wqkvT_hi = (unsigned short*)alloc(786432ULL*2);
  unsigned short* wqkvT_lo = (unsigned short*)alloc(786432ULL*2);
  unsigned short* woT_hi = (unsigned short*)alloc(262144ULL*2);
  unsigned short* woT_lo = (unsigned short*)alloc(262144ULL*2);
  unsigned short* wrT_hi = (unsigned short*)alloc(32768ULL*2);
  unsigned short* wrT_lo = (unsigned short*)alloc(32768ULL*2);
  unsigned short* h1_hi  = (unsigned short*)alloc(2097152ULL*2);
  unsigned short* h1_lo  = (unsigned short*)alloc(2097152ULL*2);
  unsigned short* h1b    = (unsigned short*)alloc(2097152ULL*2);
  float* hbuf   = (float*)alloc(2097152ULL*4);
  float* fixo   = (float*)alloc(1024ULL*512*4);
  float* logits = (float*)alloc(262144ULL*4);
  float* probs  = (float*)alloc(262144ULL*4);
  int*   idx    = (int*)alloc(24576ULL*4);
  float* wts    = (float*)alloc(24576ULL*4);
  int*   slot_of= (int*)alloc(24576ULL*4);
  int*   cnt     = (int*)alloc(256);
  int*   cursor  = (int*)alloc(256);
  int*   flagcnt = (int*)alloc(256);
  int*   flaglist= (int*)alloc(1024*4);
  int*   offs   = (int*)alloc(65*4);
  int*   ntl    = (int*)alloc(256);
  float* sumP   = (float*)alloc(64*4);
  int2*  tiles  = (int2*)alloc(512*8);
  int*   rowsl  = (int*)alloc(24576ULL*4);
  float* wrowl  = (float*)alloc(24576ULL*4);

  size_t region = off;
  size_t oA = region, oF = region;
  auto allocV = [&](size_t b, size_t& o2)->char*{
    char* p = base + o2; o2 = (o2 + b + 255) & ~(size_t)255; return p;
  };
  // attention view (~335 MB)
  float* qkv    = (float*)allocV(6291456ULL*4, oA);
  unsigned short* qkv_hi = (unsigned short*)allocV(6291456ULL*2, oA);
  unsigned short* qkv_lo = (unsigned short*)allocV(6291456ULL*2, oA);
  unsigned short* vT_hi  = (unsigned short*)allocV(2097152ULL*2, oA);
  unsigned short* vT_lo  = (unsigned short*)allocV(2097152ULL*2, oA);
  float* scores = (float*)allocV(33554432ULL*4, oA);           // [32][1024][1024]
  unsigned short* p_hi = (unsigned short*)allocV(33554432ULL*2, oA);
  unsigned short* p_lo = (unsigned short*)allocV(33554432ULL*2, oA);
  unsigned short* attno_hi = (unsigned short*)allocV(2097152ULL*2, oA);
  unsigned short* attno_lo = (unsigned short*)allocV(2097152ULL*2, oA);
  float* attnw = (float*)allocV(2097152ULL*4, oA);
  // FFN view (~382 MB)
  unsigned short* wguT = (unsigned short*)allocV(100663296ULL*2, oF);
  unsigned short* sguT = (unsigned short*)allocV(3145728ULL*2, oF);
  unsigned short* xg   = (unsigned short*)allocV(12582912ULL*2, oF);
  unsigned short* hact = (unsigned short*)allocV(37748736ULL*2, oF);
  unsigned short* shact= (unsigned short*)allocV(12582912ULL*2, oF);
  float* dout  = (float*)allocV(12582912ULL*4, oF);
  float* sdout = (float*)allocV(4194304ULL*4, oF);
  unsigned short* wdT  = wguT;
  unsigned short* swdT = wguT + 50331648ULL;

  hipMemsetAsync(cnt, 0, 768, stream);

  ksplit<<<2048, 256, 0, stream>>>(x, x_hi, x_lo, 524288);
  kTsplit<<<dim3(24,8), 256, 0, stream>>>(w_qkv, wqkvT_hi, wqkvT_lo, 512, 1536);
  kTsplit<<<dim3(8,8),  256, 0, stream>>>(w_o, woT_hi, woT_lo, 512, 512);
  kTsplit<<<dim3(1,8),  256, 0, stream>>>(router_w, wrT_hi, wrT_lo, 512, 64);

  gemm_x3<2,2,4,4,0><<<dim3(32,12,1), 256, 0, stream>>>(x_hi, x_lo, wqkvT_hi, wqkvT_lo,
      qkv, nullptr, nullptr, 512, 512, 512, 1536, 1.0f, 0,0,1, 0,0,1, 0,0,1);
  krope<<<4096, 256, 0, stream>>>(qkv, qkv_hi, qkv_lo, cosb, sinb);
  kvtrans<<<dim3(16,32), 256, 0, stream>>>(qkv, vT_hi, vT_lo);

  // scores for all 32 (b,h) in one launch: z = b*8 + h
  gemm_x3<2,2,4,4,0><<<dim3(8,8,32), 256, 0, stream>>>(qkv_hi, qkv_lo, qkv_hi+512, qkv_lo+512,
      scores, nullptr, nullptr, 64, 1536, 1536, 1024, 0.125f,
      1572864LL,64,8, 1572864LL,64,8, 1048576LL,0,1);
  // softmax all rows in one launch
  ksoftmax<<<32768, 256, 0, stream>>>(scores, p_hi, p_lo);
  // PV all 32 (b,h), epilogue emits split bf16 attno directly
  gemm_x3<2,2,2,2,1><<<dim3(16,1,32), 256, 0, stream>>>(p_hi, p_lo, vT_hi, vT_lo,
      nullptr, attno_hi, attno_lo, 1024, 1024, 1024, 512, 1.0f,
      1048576LL,0,1, 65536LL,0,1, 524288LL,64,8);
  // attn = attno @ w_o
  gemm_x3<2,2,4,4,0><<<dim3(32,4,1), 256, 0, stream>>>(attno_hi, attno_lo, woT_hi, woT_lo,
      attnw, nullptr, nullptr, 512, 512, 512, 512, 1.0f, 0,0,1, 0,0,1, 0,0,1);
  krms1<<<4096, 128, 0, stream>>>(x, attnw, h1_hi, h1_lo, h1b, hbuf);
  gemm_x3<2,2,2,2,0><<<dim3(64,1,1), 256, 0, stream>>>(h1_hi, h1_lo, wrT_hi, wrT_lo,
      logits, nullptr, nullptr, 512, 512, 512, 64, 1.0f, 0,0,1, 0,0,1, 0,0,1);
  krouter<<<1024, 256, 0, stream>>>(logits, probs, idx, wts, flagcnt, flaglist);
  kfix_attn<<<dim3(1024,8), 256, 0, stream>>>(flagcnt, flaglist, qkv, fixo);
  kfix_route<<<1024, 256, 0, stream>>>(flagcnt, flaglist, fixo, x, w_o, router_w, idx, wts, probs);
  kcount<<<96, 256, 0, stream>>>(idx, cnt);
  ksump<<<64, 256, 0, stream>>>(probs, sumP);
  kfinalize<<<1, 64, 0, stream>>>(cnt, offs, tiles, ntl);
  kscatter<<<96, 256, 0, stream>>>(idx, wts, offs, cursor, rowsl, wrowl, slot_of);

  // ---- FFN phase ----
  kgather<<<6144, 256, 0, stream>>>(h1b, rowsl, xg);
  kconvT<true><<<dim3(48,8,64), 256, 0, stream>>>(r_wgu, wguT, 512, 3072);
  kconvT<true><<<dim3(48,8,2),  256, 0, stream>>>(s_wgu, sguT, 512, 3072);
  gemm_ffn<0><<<6144, 256, 0, stream>>>(xg, wguT, hact, nullptr, offs, tiles, ntl, 3072, 512);
  gemm_ffn<2><<<dim3(32,24,2), 256, 0, stream>>>(h1b, sguT, shact, nullptr, offs, tiles, ntl, 3072, 512);
  kconvT<false><<<dim3(8,24,64), 256, 0, stream>>>(r_wd, wdT, 1536, 512);
  kconvT<false><<<dim3(8,24,2),  256, 0, stream>>>(s_wd, swdT, 1536, 512);
  gemm_ffn<1><<<1024, 256, 0, stream>>>(hact, wdT, nullptr, dout, offs, tiles, ntl, 512, 1536);
  gemm_ffn<3><<<dim3(32,4,2), 256, 0, stream>>>(shact, swdT, nullptr, sdout, offs, tiles, ntl, 512, 1536);

  kreduce<<<4096, 128, 0, stream>>>(hbuf, sdout, dout, slot_of, wts, out);
  kscalars<<<1, 64, 0, stream>>>(cnt, sumP, out + 2097152);
}

// Round 9
// 1243.274 us; speedup vs baseline: 1.1275x; 1.1089x over previous
//
// Round 9: fix wdT allocation (50,331,648 elems, was 33,554,432 -> kconvT overflow
// clobbered swdT/wdT, the round-7/8 failure). Restore kflash fused attention
// (exonerated by identical-absmax bisect evidence). Keep bf16 down-outputs,
// fused counting, un-aliased workspace (~815 MB).
#include <hip/hip_runtime.h>
#include <math.h>

#define TOK   4096
#define SEQL  1024
#define HID   512
#define NEXP  64
#define FFI   1536

typedef short bf16x8v __attribute__((ext_vector_type(8)));
typedef float f32x4   __attribute__((ext_vector_type(4)));

__device__ __forceinline__ unsigned short f2bf(float f){
  unsigned int u = __float_as_uint(f);
  u += 0x7fffu + ((u >> 16) & 1u);
  return (unsigned short)(u >> 16);
}
__device__ __forceinline__ float bf2f(unsigned short s){
  return __uint_as_float(((unsigned int)s) << 16);
}
__device__ __forceinline__ void split2(float v, unsigned short& h, unsigned short& l){
  h = f2bf(v);
  l = f2bf(v - bf2f(h));
}
__device__ __forceinline__ void gload16(const void* g, void* l){
  __builtin_amdgcn_global_load_lds(
      (const __attribute__((address_space(1))) unsigned int*)g,
      (__attribute__((address_space(3))) unsigned int*)l, 16, 0, 0);
}
__device__ __forceinline__ int xcd_swizzle(int raw, int total){
  int q = total >> 3, r = total & 7;
  int xcd = raw & 7, pos = raw >> 3;
  int csz = (xcd < r) ? (q + 1) : q;
  if (pos >= csz) return -1;
  int basel = (xcd < r) ? xcd * (q + 1) : r * (q + 1) + (xcd - r) * q;
  return basel + pos;
}

// ---------------- elementwise split fp32 -> hi/lo bf16 ----------------
__global__ __launch_bounds__(256) void ksplit(const float* __restrict__ in,
    unsigned short* __restrict__ hi, unsigned short* __restrict__ lo, int n4){
  int g = blockIdx.x*256 + threadIdx.x;
  if (g >= n4) return;
  float4 v = *(const float4*)&in[(long long)g*4];
  unsigned short h0,h1,h2,h3,l0,l1,l2,l3;
  split2(v.x,h0,l0); split2(v.y,h1,l1); split2(v.z,h2,l2); split2(v.w,h3,l3);
  *(ushort4*)&hi[(long long)g*4] = make_ushort4(h0,h1,h2,h3);
  *(ushort4*)&lo[(long long)g*4] = make_ushort4(l0,l1,l2,l3);
}

// ---------------- transpose + split: fp32 [R][C] -> hi/lo bf16 [C][R] ----------------
__global__ __launch_bounds__(256) void kTsplit(const float* __restrict__ in,
    unsigned short* __restrict__ ohi, unsigned short* __restrict__ olo, int R, int C){
  __shared__ float tile[64][65];
  int c0 = blockIdx.x*64, r0 = blockIdx.y*64;
  int tid = threadIdx.x;
  #pragma unroll
  for (int it=0; it<4; it++){
    int idx = it*256+tid; int r = idx>>4; int cq = (idx&15)*4;
    float4 v = *(const float4*)&in[(long long)(r0+r)*C + c0 + cq];
    tile[r][cq]=v.x; tile[r][cq+1]=v.y; tile[r][cq+2]=v.z; tile[r][cq+3]=v.w;
  }
  __syncthreads();
  #pragma unroll
  for (int it=0; it<2; it++){
    int idx = it*256+tid; int c = idx>>3; int rq=(idx&7)*8;
    unsigned short th[8] __attribute__((aligned(16)));
    unsigned short tl[8] __attribute__((aligned(16)));
    #pragma unroll
    for (int j=0;j<8;j++) split2(tile[rq+j][c], th[j], tl[j]);
    long long o = (long long)(c0+c)*R + r0 + rq;
    *(uint4*)&ohi[o] = *(uint4*)th;
    *(uint4*)&olo[o] = *(uint4*)tl;
  }
}

// -------- weight convert+transpose fp32 [Z][R][C] -> bf16 [Z][C][R]; optional pairing --------
template<bool PAIRED>
__global__ __launch_bounds__(256) void kconvT(const float* __restrict__ in,
    unsigned short* __restrict__ out, int R, int C){
  __shared__ float tile[64][65];
  long long zb = (long long)blockIdx.z * R * C;
  int c0 = blockIdx.x*64, r0 = blockIdx.y*64;
  int tid = threadIdx.x;
  #pragma unroll
  for (int it=0; it<4; it++){
    int idx = it*256+tid; int r = idx>>4; int cq = (idx&15)*4;
    float4 v = *(const float4*)&in[zb + (long long)(r0+r)*C + c0 + cq];
    tile[r][cq]=v.x; tile[r][cq+1]=v.y; tile[r][cq+2]=v.z; tile[r][cq+3]=v.w;
  }
  __syncthreads();
  #pragma unroll
  for (int it=0; it<2; it++){
    int idx = it*256+tid; int c = idx>>3; int rq=(idx&7)*8;
    unsigned short tb[8] __attribute__((aligned(16)));
    #pragma unroll
    for (int j=0;j<8;j++) tb[j] = f2bf(tile[rq+j][c]);
    int cc = c0 + c;
    int orow = PAIRED ? ((cc < (C>>1)) ? 2*cc : 2*(cc-(C>>1))+1) : cc;
    *(uint4*)&out[zb + (long long)orow*R + r0 + rq] = *(uint4*)tb;
  }
}

// ---------------- bf16x3 TN GEMM: C = alpha * (Ahi+Alo)(Bhi+Blo)^T (drop lo*lo) ----------------
template<int WM,int WN,int FM,int FN>
__global__ __launch_bounds__(256) void gemm_x3(
    const unsigned short* __restrict__ Ahi, const unsigned short* __restrict__ Alo,
    const unsigned short* __restrict__ Bhi, const unsigned short* __restrict__ Blo,
    float* __restrict__ C,
    int K, int lda, int ldb, int ldc, float alpha,
    long long a1, long long a2, int adiv,
    long long b1, long long b2, int bdiv,
    long long c1, long long c2, int cdiv)
{
  constexpr int BM = WM*FM*16, BN = WN*FN*16;
  constexpr int AIT = (2*BM*4)/256, BIT = (2*BN*4)/256;
  int z = blockIdx.z;
  long long aoff = (long long)(z/adiv)*a1 + (long long)(z%adiv)*a2;
  long long boff = (long long)(z/bdiv)*b1 + (long long)(z%bdiv)*b2;
  long long coff = (long long)(z/cdiv)*c1 + (long long)(z%cdiv)*c2;
  int m0 = blockIdx.x*BM, n0 = blockIdx.y*BN;
  __shared__ __align__(16) unsigned short As[2][BM*40];
  __shared__ __align__(16) unsigned short Bs[2][BN*40];
  int tid = threadIdx.x, lane = tid&63, wid = tid>>6;
  int wr = wid / WN, wc = wid % WN;
  int lrow = lane&15, kgo = (lane>>4)*8;
  f32x4 acc[FM][FN];
  #pragma unroll
  for (int mi=0;mi<FM;mi++)
    #pragma unroll
    for (int nj=0;nj<FN;nj++) acc[mi][nj] = (f32x4){0.f,0.f,0.f,0.f};

  for (int k0=0; k0<K; k0+=32){
    uint4 ta[AIT], tb[BIT];
    #pragma unroll
    for (int it=0; it<AIT; it++){
      int c = it*256+tid; int pl = c/(BM*4); int rem = c%(BM*4);
      int row = rem>>2, q = (rem&3)*8;
      const unsigned short* src = pl ? Alo : Ahi;
      ta[it] = *(const uint4*)&src[aoff + (long long)(m0+row)*lda + k0 + q];
    }
    #pragma unroll
    for (int it=0; it<BIT; it++){
      int c = it*256+tid; int pl = c/(BN*4); int rem = c%(BN*4);
      int row = rem>>2, q = (rem&3)*8;
      const unsigned short* src = pl ? Blo : Bhi;
      tb[it] = *(const uint4*)&src[boff + (long long)(n0+row)*ldb + k0 + q];
    }
    __syncthreads();
    #pragma unroll
    for (int it=0; it<AIT; it++){
      int c = it*256+tid; int pl = c/(BM*4); int rem = c%(BM*4);
      int row = rem>>2, q = (rem&3)*8;
      *(uint4*)&As[pl][row*40+q] = ta[it];
    }
    #pragma unroll
    for (int it=0; it<BIT; it++){
      int c = it*256+tid; int pl = c/(BN*4); int rem = c%(BN*4);
      int row = rem>>2, q = (rem&3)*8;
      *(uint4*)&Bs[pl][row*40+q] = tb[it];
    }
    __syncthreads();
    bf16x8v ah[FM], al[FM], bh[FN], bl[FN];
    int ab = (wr*FM*16 + lrow)*40 + kgo;
    int bb = (wc*FN*16 + lrow)*40 + kgo;
    #pragma unroll
    for (int mi=0;mi<FM;mi++){
      ah[mi] = *(const bf16x8v*)&As[0][ab + mi*640];
      al[mi] = *(const bf16x8v*)&As[1][ab + mi*640];
    }
    #pragma unroll
    for (int nj=0;nj<FN;nj++){
      bh[nj] = *(const bf16x8v*)&Bs[0][bb + nj*640];
      bl[nj] = *(const bf16x8v*)&Bs[1][bb + nj*640];
    }
    #pragma unroll
    for (int mi=0;mi<FM;mi++)
      #pragma unroll
      for (int nj=0;nj<FN;nj++){
        acc[mi][nj] = __builtin_amdgcn_mfma_f32_16x16x32_bf16(ah[mi], bh[nj], acc[mi][nj], 0,0,0);
        acc[mi][nj] = __builtin_amdgcn_mfma_f32_16x16x32_bf16(ah[mi], bl[nj], acc[mi][nj], 0,0,0);
        acc[mi][nj] = __builtin_amdgcn_mfma_f32_16x16x32_bf16(al[mi], bh[nj], acc[mi][nj], 0,0,0);
      }
  }
  int crow = m0 + wr*FM*16 + ((lane>>4)<<2);
  int ccol = n0 + wc*FN*16 + (lane&15);
  #pragma unroll
  for (int mi=0;mi<FM;mi++)
    #pragma unroll
    for (int r=0;r<4;r++){
      long long row = crow + mi*16 + r;
      #pragma unroll
      for (int nj=0;nj<FN;nj++)
        C[coff + row*ldc + ccol + nj*16] = alpha*acc[mi][nj][r];
    }
}

// ---------------- RoPE: rotate q,k in fp32 (write back) + split to hi/lo ----------------
__global__ __launch_bounds__(256) void krope(float* __restrict__ qkv,
    unsigned short* __restrict__ qhi, unsigned short* __restrict__ qlo,
    const float* __restrict__ cosb, const float* __restrict__ sinb){
  int gid = blockIdx.x*256 + threadIdx.x;
  int t = gid >> 8; int rem = gid & 255; int h = rem >> 5; int d = rem & 31;
  int s = t & (SEQL-1);
  long long base = (long long)t*1536 + h*64;
  float c1 = cosb[s*64+d], c2 = cosb[s*64+d+32];
  float s1 = sinb[s*64+d], s2 = sinb[s*64+d+32];
  float q1 = qkv[base+d], q2 = qkv[base+d+32];
  float rq1 = q1*c1 - q2*s1, rq2 = q2*c2 + q1*s2;
  qkv[base+d] = rq1; qkv[base+d+32] = rq2;
  split2(rq1, qhi[base+d],    qlo[base+d]);
  split2(rq2, qhi[base+d+32], qlo[base+d+32]);
  float k1 = qkv[base+512+d], k2 = qkv[base+512+d+32];
  float rk1 = k1*c1 - k2*s1, rk2 = k2*c2 + k1*s2;
  qkv[base+512+d] = rk1; qkv[base+512+d+32] = rk2;
  split2(rk1, qhi[base+512+d],    qlo[base+512+d]);
  split2(rk2, qhi[base+512+d+32], qlo[base+512+d+32]);
}

// ---------------- V transpose ----------------
__global__ __launch_bounds__(256) void kvtrans(const float* __restrict__ qkv,
    unsigned short* __restrict__ vhi, unsigned short* __restrict__ vlo){
  __shared__ float tile[64][65];
  int s0 = blockIdx.x*64;
  int z = blockIdx.y;
  int b = z >> 3, h = z & 7;
  int tid = threadIdx.x;
  #pragma unroll
  for (int it=0; it<4; it++){
    int idx = it*256+tid; int r = idx>>4; int cq = (idx&15)*4;
    float4 v = *(const float4*)&qkv[((long long)(b*1024 + s0 + r))*1536 + 1024 + h*64 + cq];
    tile[r][cq]=v.x; tile[r][cq+1]=v.y; tile[r][cq+2]=v.z; tile[r][cq+3]=v.w;
  }
  __syncthreads();
  #pragma unroll
  for (int it=0; it<2; it++){
    int idx = it*256+tid; int d = idx>>3; int sq = (idx&7)*8;
    unsigned short th[8] __attribute__((aligned(16)));
    unsigned short tl[8] __attribute__((aligned(16)));
    #pragma unroll
    for (int j=0;j<8;j++) split2(tile[sq+j][d], th[j], tl[j]);
    long long o = ((long long)(z*64 + d))*1024 + s0 + sq;
    *(uint4*)&vhi[o] = *(uint4*)th;
    *(uint4*)&vlo[o] = *(uint4*)tl;
  }
}

// ---------------- fused flash attention (x3 precision), Q-tile 64, KV-tile 64 ----------------
// grid (16 qtiles, 32 bh), 256 threads = 4 waves, wave w owns q rows [qt*64+w*16, +16)
__global__ __launch_bounds__(256) void kflash(
    const unsigned short* __restrict__ qkv_hi, const unsigned short* __restrict__ qkv_lo,
    const unsigned short* __restrict__ vT_hi,  const unsigned short* __restrict__ vT_lo,
    unsigned short* __restrict__ attno_hi, unsigned short* __restrict__ attno_lo)
{
  int qt = blockIdx.x;
  int z  = blockIdx.y;
  int b = z >> 3, h = z & 7;
  int tid = threadIdx.x, lane = tid & 63, w = tid >> 6;
  int q0 = qt*64 + w*16;
  int fr = lane & 15;
  int fk = (lane >> 4) * 8;

  long long qbase  = ((long long)(b*1024 + q0 + fr))*1536 + h*64;
  long long kbhb   = ((long long)b*1024)*1536 + 512 + h*64;
  long long vbase  = ((long long)z*64)*1024;

  bf16x8v qa_h[2], qa_l[2];
  qa_h[0] = *(const bf16x8v*)&qkv_hi[qbase + fk];
  qa_h[1] = *(const bf16x8v*)&qkv_hi[qbase + 32 + fk];
  qa_l[0] = *(const bf16x8v*)&qkv_lo[qbase + fk];
  qa_l[1] = *(const bf16x8v*)&qkv_lo[qbase + 32 + fk];

  __shared__ __align__(16) unsigned short Ph[4][16*64];
  __shared__ __align__(16) unsigned short Pl[4][16*64];

  float m_run[4], l_run[4];
  #pragma unroll
  for (int r=0;r<4;r++){ m_run[r] = -1e30f; l_run[r] = 0.f; }
  f32x4 oacc[4];
  #pragma unroll
  for (int nj=0;nj<4;nj++) oacc[nj] = (f32x4){0.f,0.f,0.f,0.f};

  for (int kt = 0; kt < 16; kt++){
    int kv0 = kt*64;
    f32x4 s[4];
    #pragma unroll
    for (int nj=0;nj<4;nj++) s[nj] = (f32x4){0.f,0.f,0.f,0.f};
    #pragma unroll
    for (int nj=0;nj<4;nj++){
      long long kr = kbhb + (long long)(kv0 + nj*16 + fr)*1536;
      #pragma unroll
      for (int kd=0; kd<2; kd++){
        bf16x8v kb_h = *(const bf16x8v*)&qkv_hi[kr + kd*32 + fk];
        bf16x8v kb_l = *(const bf16x8v*)&qkv_lo[kr + kd*32 + fk];
        s[nj] = __builtin_amdgcn_mfma_f32_16x16x32_bf16(qa_h[kd], kb_h, s[nj], 0,0,0);
        s[nj] = __builtin_amdgcn_mfma_f32_16x16x32_bf16(qa_h[kd], kb_l, s[nj], 0,0,0);
        s[nj] = __builtin_amdgcn_mfma_f32_16x16x32_bf16(qa_l[kd], kb_h, s[nj], 0,0,0);
      }
    }
    // scale + row max (q-row = (lane>>4)*4 + r; 16 lanes of a row-group hold the kv cols)
    #pragma unroll
    for (int r=0;r<4;r++){
      float mx = -1e30f;
      #pragma unroll
      for (int nj=0;nj<4;nj++){ s[nj][r] *= 0.125f; mx = fmaxf(mx, s[nj][r]); }
      #pragma unroll
      for (int o=1;o<16;o<<=1) mx = fmaxf(mx, __shfl_xor(mx, o));
      float mnew = fmaxf(m_run[r], mx);
      float sc = __expf(m_run[r] - mnew);
      m_run[r] = mnew;
      l_run[r] *= sc;
      #pragma unroll
      for (int nj=0;nj<4;nj++) oacc[nj][r] *= sc;
    }
    // P = exp(S-m): partial row sums + wave-local LDS write (hi/lo)
    #pragma unroll
    for (int nj=0;nj<4;nj++){
      #pragma unroll
      for (int r=0;r<4;r++){
        float p = __expf(s[nj][r] - m_run[r]);
        l_run[r] += p;
        unsigned short ph, pl;
        split2(p, ph, pl);
        int row = (lane>>4)*4 + r;
        int col = nj*16 + fr;
        Ph[w][row*64+col] = ph;
        Pl[w][row*64+col] = pl;
      }
    }
    // PV: A-frags from wave-local LDS (same-wave ds ordering), B-frags (V^T) from global
    #pragma unroll
    for (int ks=0; ks<2; ks++){
      bf16x8v pa_h = *(const bf16x8v*)&Ph[w][fr*64 + ks*32 + fk];
      bf16x8v pa_l = *(const bf16x8v*)&Pl[w][fr*64 + ks*32 + fk];
      #pragma unroll
      for (int nj=0;nj<4;nj++){
        long long vr = vbase + (long long)(nj*16 + fr)*1024 + kv0 + ks*32 + fk;
        bf16x8v vb_h = *(const bf16x8v*)&vT_hi[vr];
        bf16x8v vb_l = *(const bf16x8v*)&vT_lo[vr];
        oacc[nj] = __builtin_amdgcn_mfma_f32_16x16x32_bf16(pa_h, vb_h, oacc[nj], 0,0,0);
        oacc[nj] = __builtin_amdgcn_mfma_f32_16x16x32_bf16(pa_h, vb_l, oacc[nj], 0,0,0);
        oacc[nj] = __builtin_amdgcn_mfma_f32_16x16x32_bf16(pa_l, vb_h, oacc[nj], 0,0,0);
      }
    }
  }
  // finalize: reduce partial l across the 16-lane row-group, normalize, store split
  #pragma unroll
  for (int r=0;r<4;r++){
    float l = l_run[r];
    #pragma unroll
    for (int o=1;o<16;o<<=1) l += __shfl_xor(l, o);
    float inv = 1.0f / l;
    int row = (lane>>4)*4 + r;
    long long tok = (long long)(b*1024 + qt*64 + w*16 + row);
    #pragma unroll
    for (int nj=0;nj<4;nj++){
      float v = oacc[nj][r] * inv;
      unsigned short hh, ll;
      split2(v, hh, ll);
      attno_hi[tok*512 + h*64 + nj*16 + fr] = hh;
      attno_lo[tok*512 + h*64 + nj*16 + fr] = ll;
    }
  }
}

// ---------------- rms_norm(x+attn) -> h1 hi/lo + h1b + hbuf(f32) ----------------
__global__ __launch_bounds__(128) void krms1(const float* __restrict__ x, const float* __restrict__ attn,
    unsigned short* __restrict__ h1hi, unsigned short* __restrict__ h1lo,
    unsigned short* __restrict__ h1b, float* __restrict__ hbuf){
  long long row = blockIdx.x;
  int tid = threadIdx.x;
  float4 xv = *(const float4*)&x[row*512 + tid*4];
  float4 av = *(const float4*)&attn[row*512 + tid*4];
  float4 v; v.x=xv.x+av.x; v.y=xv.y+av.y; v.z=xv.z+av.z; v.w=xv.w+av.w;
  float ss = v.x*v.x + v.y*v.y + v.z*v.z + v.w*v.w;
  for (int o=32;o>0;o>>=1) ss += __shfl_xor(ss,o);
  __shared__ float red[2];
  int wid = tid>>6, lane = tid&63;
  if (lane==0) red[wid]=ss;
  __syncthreads();
  ss = red[0]+red[1];
  float r = 1.0f/sqrtf(ss*(1.0f/512.0f) + 1e-5f);
  float4 o; o.x=v.x*r; o.y=v.y*r; o.z=v.z*r; o.w=v.w*r;
  *(float4*)&hbuf[row*512 + tid*4] = o;
  unsigned short h0,h1,h2,h3,l0,l1,l2,l3;
  split2(o.x,h0,l0); split2(o.y,h1,l1); split2(o.z,h2,l2); split2(o.w,h3,l3);
  *(ushort4*)&h1hi[row*512 + tid*4] = make_ushort4(h0,h1,h2,h3);
  *(ushort4*)&h1lo[row*512 + tid*4] = make_ushort4(l0,l1,l2,l3);
  *(ushort4*)&h1b[row*512 + tid*4] = make_ushort4(f2bf(o.x),f2bf(o.y),f2bf(o.z),f2bf(o.w));
}

// ---------------- routing decision (one 64-lane wave per token) ----------------
__device__ void route_decide(float p, int e, int t,
    int* __restrict__ idx, float* __restrict__ wts, int* __restrict__ cntp,
    int* __restrict__ flagcnt, int* __restrict__ flaglist){
  float d = p;
  d += __shfl_xor(d,1); d += __shfl_xor(d,2); d += __shfl_xor(d,4);
  int g = e >> 3;
  float gs[8];
  #pragma unroll
  for (int j=0;j<8;j++) gs[j] = __shfl(d, j*8);
  int rank = 0;
  #pragma unroll
  for (int j=0;j<8;j++) rank += (gs[j] > d) || (gs[j] == d && j < g);
  float q = (rank < 3) ? p : -INFINITY;
  float svals[7]; int sidx[7];
  #pragma unroll
  for (int kk=0; kk<7; kk++){
    float v = q; int vi = e;
    for (int o=32;o>0;o>>=1){
      float ov = __shfl_xor(v,o); int oi = __shfl_xor(vi,o);
      if (ov > v || (ov == v && oi < vi)){ v = ov; vi = oi; }
    }
    svals[kk] = v; sidx[kk] = vi;
    if (e == vi) q = -INFINITY;
  }
  float mx = svals[0], tot = 0.f, wv[6];
  #pragma unroll
  for (int kk=0;kk<6;kk++){ wv[kk] = expf(svals[kk]-mx); tot += wv[kk]; }
  if (e < 6){
    idx[t*6+e] = sidx[e];
    wts[t*6+e] = wv[e]/tot;
    if (cntp) atomicAdd(&cntp[sidx[e]], 1);
  }
  if (flagcnt != nullptr && e == 0){
    float a[8];
    #pragma unroll
    for (int j=0;j<8;j++) a[j] = gs[j];
    float t3=-1e30f, t4=-1e30f;
    for (int it2=0; it2<4; it2++){
      int bi=0; float bv=a[0];
      #pragma unroll
      for (int j=1;j<8;j++) if (a[j] > bv){ bv=a[j]; bi=j; }
      if (it2==2) t3=bv;
      if (it2==3) t4=bv;
      a[bi] = -1e30f;
    }
    float pgap = svals[5] - svals[6];
    float dgap = t3 - t4;
    if (pgap < 1e-4f || dgap < 5e-4f){
      int pos = atomicAdd(flagcnt, 1);
      if (pos < 1024) flaglist[pos] = t;
    }
  }
}

__global__ __launch_bounds__(256) void krouter(const float* __restrict__ logits,
    float* __restrict__ probs, int* __restrict__ idx, float* __restrict__ wts,
    int* __restrict__ cnt, int* __restrict__ flagcnt, int* __restrict__ flaglist){
  int t = blockIdx.x*4 + (threadIdx.x >> 6);
  int e = threadIdx.x & 63;
  float l = logits[t*64 + e];
  float m = l;
  for (int o=32;o>0;o>>=1) m = fmaxf(m, __shfl_xor(m,o));
  float p = expf(l-m);
  float s = p;
  for (int o=32;o>0;o>>=1) s += __shfl_xor(s,o);
  p /= s;
  probs[t*64+e] = p;
  route_decide(p, e, t, idx, wts, cnt, flagcnt, flaglist);
}

// ---------------- exact fp32 attention recompute, one block per (flag, head) ----------------
__global__ __launch_bounds__(256) void kfix_attn(const int* __restrict__ flagcnt,
    const int* __restrict__ flaglist, const float* __restrict__ qkv, float* __restrict__ fixo){
  int fc = *flagcnt; if (fc > 1024) fc = 1024;
  if ((int)blockIdx.x >= fc) return;
  int t = flaglist[blockIdx.x];
  int h = blockIdx.y;
  int b = t >> 10;
  int tid = threadIdx.x, lane = tid & 63, w = tid >> 6;
  __shared__ float sc[1024];
  __shared__ float qh[64];
  __shared__ float red[4];
  __shared__ float op[4][64];
  __shared__ float sinv;
  if (tid < 64) qh[tid] = qkv[(long long)t*1536 + h*64 + tid];
  __syncthreads();
  float q = qh[lane];
  const float* kb = qkv + (long long)b*1024*1536 + 512 + h*64 + lane;
  for (int s0 = w*256; s0 < w*256 + 256; s0 += 8){
    float p[8];
    #pragma unroll
    for (int j=0;j<8;j++) p[j] = q * kb[(long long)(s0+j)*1536];
    #pragma unroll
    for (int o=32;o>0;o>>=1){
      #pragma unroll
      for (int j=0;j<8;j++) p[j] += __shfl_xor(p[j],o);
    }
    if (lane == 0){
      #pragma unroll
      for (int j=0;j<8;j++) sc[s0+j] = p[j] * 0.125f;
    }
  }
  __syncthreads();
  float m = -1e30f;
  for (int s = tid; s < 1024; s += 256) m = fmaxf(m, sc[s]);
  #pragma unroll
  for (int o=32;o>0;o>>=1) m = fmaxf(m, __shfl_xor(m,o));
  if (lane == 0) red[w] = m;
  __syncthreads();
  m = fmaxf(fmaxf(red[0],red[1]), fmaxf(red[2],red[3]));
  __syncthreads();
  float sum = 0.f;
  for (int s = tid; s < 1024; s += 256){ float e = expf(sc[s]-m); sc[s] = e; sum += e; }
  #pragma unroll
  for (int o=32;o>0;o>>=1) sum += __shfl_xor(sum,o);
  if (lane == 0) red[w] = sum;
  __syncthreads();
  if (tid == 0) sinv = 1.0f/(red[0]+red[1]+red[2]+red[3]);
  const float* vb = qkv + (long long)b*1024*1536 + 1024 + h*64 + lane;
  float a0 = 0.f, a1 = 0.f, a2 = 0.f, a3 = 0.f;
  for (int s = w*256; s < w*256 + 256; s += 4){
    a0 += sc[s]   * vb[(long long)(s)*1536];
    a1 += sc[s+1] * vb[(long long)(s+1)*1536];
    a2 += sc[s+2] * vb[(long long)(s+2)*1536];
    a3 += sc[s+3] * vb[(long long)(s+3)*1536];
  }
  op[w][lane] = (a0+a1)+(a2+a3);
  __syncthreads();
  if (tid < 64)
    fixo[(long long)blockIdx.x*512 + h*64 + tid] =
      (op[0][tid]+op[1][tid]+op[2][tid]+op[3][tid]) * sinv;
}

// ---------------- exact fp32 w_o + rms + router for flagged tokens ----------------
__global__ __launch_bounds__(256) void kfix_route(const int* __restrict__ flagcnt,
    const int* __restrict__ flaglist, const float* __restrict__ fixo,
    const float* __restrict__ x, const float* __restrict__ w_o, const float* __restrict__ router_w,
    int* __restrict__ idx, float* __restrict__ wts, float* __restrict__ probs, int* __restrict__ cnt){
  int fc = *flagcnt; if (fc > 1024) fc = 1024;
  if ((int)blockIdx.x >= fc) return;
  int t = flaglist[blockIdx.x];
  int tid = threadIdx.x;
  __shared__ float o512[512];
  __shared__ float h1s[512];
  __shared__ float red[4];
  o512[tid]     = fixo[(long long)blockIdx.x*512 + tid];
  o512[tid+256] = fixo[(long long)blockIdx.x*512 + tid + 256];
  __syncthreads();
  int j0 = tid, j1 = tid + 256;
  float a0 = 0.f, a1 = 0.f;
  #pragma unroll 4
  for (int i = 0; i < 512; i++){
    float oi = o512[i];
    a0 += oi * w_o[(long long)i*512 + j0];
    a1 += oi * w_o[(long long)i*512 + j1];
  }
  float hj0 = x[(long long)t*512 + j0] + a0;
  float hj1 = x[(long long)t*512 + j1] + a1;
  float ss = hj0*hj0 + hj1*hj1;
  #pragma unroll
  for (int o=32;o>0;o>>=1) ss += __shfl_xor(ss,o);
  if ((tid&63)==0) red[tid>>6]=ss;
  __syncthreads();
  ss = red[0]+red[1]+red[2]+red[3];
  float r = 1.0f/sqrtf(ss*(1.0f/512.0f) + 1e-5f);
  h1s[j0] = hj0*r; h1s[j1] = hj1*r;
  __syncthreads();
  if (tid < 64){
    int e = tid;
    if (e < 6) atomicSub(&cnt[idx[t*6+e]], 1);
    float le = 0.f;
    #pragma unroll 4
    for (int i=0;i<512;i++) le += h1s[i]*router_w[(long long)i*64 + e];
    float m2 = le;
    #pragma unroll
    for (int o=32;o>0;o>>=1) m2 = fmaxf(m2, __shfl_xor(m2,o));
    float p = expf(le - m2), s2 = p;
    #pragma unroll
    for (int o=32;o>0;o>>=1) s2 += __shfl_xor(s2,o);
    p /= s2;
    probs[(long long)t*64 + e] = p;
    route_decide(p, e, t, idx, wts, cnt, nullptr, nullptr);
  }
}

__global__ __launch_bounds__(256) void ksump(const float* __restrict__ probs, float* __restrict__ sumP){
  int e = blockIdx.x; int tid = threadIdx.x;
  float acc = 0.f;
  for (int t = tid; t < TOK; t += 256) acc += probs[t*64 + e];
  for (int o=32;o>0;o>>=1) acc += __shfl_xor(acc,o);
  __shared__ float red[4];
  int wid = tid>>6, lane = tid&63;
  if (lane==0) red[wid]=acc;
  __syncthreads();
  if (tid==0) sumP[e] = red[0]+red[1]+red[2]+red[3];
}

// wave-parallel prefix sums over 64 experts
__global__ void kfinalize(const int* __restrict__ cnt, int* __restrict__ offs,
                          int2* __restrict__ tiles, int* __restrict__ ntl){
  int e = threadIdx.x;
  int c = cnt[e];
  int inc = c;
  #pragma unroll
  for (int o=1;o<64;o<<=1){ int v = __shfl_up(inc,o); if (e>=o) inc += v; }
  offs[e] = inc - c;
  if (e == 63) offs[64] = inc;
  int nte = (c + 127) >> 7;
  int tinc = nte;
  #pragma unroll
  for (int o=1;o<64;o<<=1){ int v = __shfl_up(tinc,o); if (e>=o) tinc += v; }
  int tbase = tinc - nte;
  for (int i=0;i<nte;i++) tiles[tbase+i] = make_int2(e, i*128);
  if (e == 63) *ntl = tinc;
}

__global__ __launch_bounds__(256) void kscatter(const int* __restrict__ idx, const float* __restrict__ wts,
    const int* __restrict__ offs, int* __restrict__ cursor,
    int* __restrict__ rowsl, float* __restrict__ wrowl, int* __restrict__ slot_of){
  int g = blockIdx.x*256 + threadIdx.x;
  if (g >= TOK*6) return;
  int t = g/6, kk = g%6;
  int e = idx[t*6+kk];
  int pos = atomicAdd(&cursor[e], 1);
  int slot = offs[e]+pos;
  rowsl[slot] = t;
  wrowl[slot] = wts[t*6+kk];
  slot_of[t*6+kk] = slot;
}

__global__ __launch_bounds__(256) void kgather(const unsigned short* __restrict__ h1b,
    const int* __restrict__ rowsl, unsigned short* __restrict__ xg){
  int r = blockIdx.x*4 + (threadIdx.x>>6);
  int lane = threadIdx.x&63;
  int tok = rowsl[r];
  *(uint4*)&xg[(long long)r*512 + lane*8] = *(const uint4*)&h1b[(long long)tok*512 + lane*8];
}

// ---------------- FFN bf16 MFMA GEMM (128x128, BK=32) with global_load_lds staging ----------------
// MODE 0: expert gate/up (A=xg) + fused SwiGLU -> Cout=hact [paired weights]
// MODE 1: expert down (A=hact) -> Cout=doutb (bf16)
// MODE 2: shared gate/up (A=h1b) + fused SwiGLU -> Cout=shact
// MODE 3: shared down (A=shact) -> Cout=sdoutb (bf16)
template<int MODE>
__global__ __launch_bounds__(256) void gemm_ffn(
    const unsigned short* __restrict__ Ab, const unsigned short* __restrict__ Bw,
    unsigned short* __restrict__ Cout,
    const int* __restrict__ offs, const int2* __restrict__ tiles, const int* __restrict__ ntl,
    int N, int K)
{
  int m0=0, roff=0, Me=1<<30, n0=0, zi=0;
  long long Aoff=0, Boff=0;
  int lda;
  if constexpr (MODE==0 || MODE==1){
    constexpr int NF = (MODE==0) ? 24 : 4;
    int nt = *ntl;
    int total = nt*NF;
    int l = xcd_swizzle(blockIdx.x, total);
    if (l < 0 || l >= total) return;
    int tile = l / NF; int y = l % NF;
    int2 tl = tiles[tile];
    int e = tl.x; m0 = tl.y;
    roff = offs[e]; Me = offs[e+1]-roff;
    n0 = y*128;
    Boff = (long long)e*N*K;
    lda = K;
  } else {
    m0 = blockIdx.x*128;
    n0 = blockIdx.y*128;
    zi = blockIdx.z;
    Boff = (long long)zi*N*K;
    if constexpr (MODE==2) lda = 512;
    else { lda = K; Aoff = (long long)zi*4096LL*K; }
  }
  __shared__ __align__(16) unsigned short As[128*32];
  __shared__ __align__(16) unsigned short Bs[128*32];
  int tid = threadIdx.x, lane = tid&63, wid = tid>>6;
  int wr = wid>>1, wc = wid&1;
  int lrow = lane&15, kgo = (lane>>4)*8;
  f32x4 acc[4][4];
  #pragma unroll
  for (int mi=0;mi<4;mi++)
    #pragma unroll
    for (int nj=0;nj<4;nj++) acc[mi][nj] = (f32x4){0.f,0.f,0.f,0.f};

  int g0 = wid*2, g1 = wid*2 + 1;
  int colq = (lane&3)*8;
  int ar0 = g0*16 + (lane>>2), ar1 = g1*16 + (lane>>2);
  long long abase0, abase1;
  if constexpr (MODE==0 || MODE==1){
    int r0 = roff + m0 + ar0; if (r0 > 24575) r0 = 24575;
    int r1 = roff + m0 + ar1; if (r1 > 24575) r1 = 24575;
    abase0 = (long long)r0*lda; abase1 = (long long)r1*lda;
  } else if constexpr (MODE==2){
    abase0 = (long long)(m0+ar0)*lda; abase1 = (long long)(m0+ar1)*lda;
  } else {
    abase0 = Aoff + (long long)(m0+ar0)*lda; abase1 = Aoff + (long long)(m0+ar1)*lda;
  }
  long long bbase0 = Boff + (long long)(n0+ar0)*K;
  long long bbase1 = Boff + (long long)(n0+ar1)*K;

  for (int k0=0; k0<K; k0+=32){
    __syncthreads();
    gload16(Ab + abase0 + k0 + colq, &As[g0*512]);
    gload16(Ab + abase1 + k0 + colq, &As[g1*512]);
    gload16(Bw + bbase0 + k0 + colq, &Bs[g0*512]);
    gload16(Bw + bbase1 + k0 + colq, &Bs[g1*512]);
    __syncthreads();
    bf16x8v af[4], bfv[4];
    int ab = (wr*64 + lrow)*32 + kgo;
    int bb = (wc*64 + lrow)*32 + kgo;
    #pragma unroll
    for (int mi=0;mi<4;mi++) af[mi]  = *(const bf16x8v*)&As[ab + mi*512];
    #pragma unroll
    for (int nj=0;nj<4;nj++) bfv[nj] = *(const bf16x8v*)&Bs[bb + nj*512];
    #pragma unroll
    for (int mi=0;mi<4;mi++)
      #pragma unroll
      for (int nj=0;nj<4;nj++)
        acc[mi][nj] = __builtin_amdgcn_mfma_f32_16x16x32_bf16(af[mi], bfv[nj], acc[mi][nj], 0,0,0);
  }

  int lq = lane>>4;
  int l15 = lane&15;
  if constexpr (MODE==0 || MODE==2){
    bool evenlane = (l15&1)==0;
    int pb = (n0>>1) + wc*32 + (l15>>1);
    #pragma unroll
    for (int mi=0;mi<4;mi++){
      #pragma unroll
      for (int r2=0;r2<4;r2++){
        int lr = wr*64 + mi*16 + lq*4 + r2;
        bool valid; long long grow;
        if constexpr (MODE==0){ valid = (m0+lr)<Me; grow = roff+m0+lr; }
        else { valid = true; grow = (long long)zi*4096 + m0 + lr; }
        #pragma unroll
        for (int nj=0;nj<4;nj++){
          float v = acc[mi][nj][r2];
          float o2 = __shfl_xor(v,1);
          if (evenlane && valid){
            float g = v, u = o2;
            float sg = g/(1.0f+expf(-g))*u;
            Cout[grow*1536 + pb + nj*8] = f2bf(sg);
          }
        }
      }
    }
  } else {
    #pragma unroll
    for (int mi=0;mi<4;mi++)
      #pragma unroll
      for (int r2=0;r2<4;r2++){
        int lr = wr*64 + mi*16 + lq*4 + r2;
        bool valid; long long grow;
        if constexpr (MODE==1){ valid = (m0+lr)<Me; grow = roff+m0+lr; }
        else { valid = true; grow = (long long)zi*4096 + m0 + lr; }
        if (valid){
          #pragma unroll
          for (int nj=0;nj<4;nj++)
            Cout[grow*512 + n0 + wc*64 + nj*16 + l15] = f2bf(acc[mi][nj][r2]);
        }
      }
  }
}

// ---------------- final reduce: out = rms(h1 + shared + routed), bf16 down-outputs ----------------
__global__ __launch_bounds__(128) void kreduce(const float* __restrict__ hbuf,
    const unsigned short* __restrict__ sdoutb, const unsigned short* __restrict__ doutb,
    const int* __restrict__ slot_of, const float* __restrict__ wts,
    float* __restrict__ out){
  int t = blockIdx.x;
  int tid = threadIdx.x;
  int c4 = tid*4;
  float4 s = *(const float4*)&hbuf[(long long)t*512 + c4];
  ushort4 a = *(const ushort4*)&sdoutb[(long long)t*512 + c4];
  ushort4 b2 = *(const ushort4*)&sdoutb[(long long)(4096+t)*512 + c4];
  s.x += bf2f(a.x) + bf2f(b2.x);
  s.y += bf2f(a.y) + bf2f(b2.y);
  s.z += bf2f(a.z) + bf2f(b2.z);
  s.w += bf2f(a.w) + bf2f(b2.w);
  #pragma unroll
  for (int kk=0; kk<6; kk++){
    float w = wts[t*6+kk];
    int slot = slot_of[t*6+kk];
    ushort4 d = *(const ushort4*)&doutb[(long long)slot*512 + c4];
    s.x += w*bf2f(d.x); s.y += w*bf2f(d.y); s.z += w*bf2f(d.z); s.w += w*bf2f(d.w);
  }
  float ss = s.x*s.x + s.y*s.y + s.z*s.z + s.w*s.w;
  for (int o=32;o>0;o>>=1) ss += __shfl_xor(ss,o);
  __shared__ float red[2];
  int wid = tid>>6, lane = tid&63;
  if (lane==0) red[wid]=ss;
  __syncthreads();
  ss = red[0]+red[1];
  float r = 1.0f/sqrtf(ss*(1.0f/512.0f) + 1e-5f);
  float4 o; o.x=s.x*r; o.y=s.y*r; o.z=s.z*r; o.w=s.w*r;
  *(float4*)&out[(long long)t*512 + c4] = o;
}

// ---------------- balance-loss scalars ----------------
__global__ void kscalars(const int* __restrict__ cnt, const float* __restrict__ sumP, float* __restrict__ o){
  int e = threadIdx.x;
  float cf = (float)cnt[e];
  float f = cf / 24576.0f;
  float P = sumP[e] / 4096.0f;
  float fg = f, Pg = P, cg = cf;
  fg += __shfl_xor(fg,1); fg += __shfl_xor(fg,2); fg += __shfl_xor(fg,4);
  Pg += __shfl_xor(Pg,1); Pg += __shfl_xor(Pg,2); Pg += __shfl_xor(Pg,4);
  cg += __shfl_xor(cg,1); cg += __shfl_xor(cg,2); cg += __shfl_xor(cg,4);
  float t1 = f*P;
  float t2 = ((e&7)==0) ? (fg/8.0f)*Pg : 0.0f;
  float t3 = ((e&7)==0) ? (cg/12288.0f)*Pg : 0.0f;
  for (int s=32;s>0;s>>=1){
    t1 += __shfl_xor(t1,s); t2 += __shfl_xor(t2,s); t3 += __shfl_xor(t3,s);
  }
  if (e==0){
    float ebl = t1*0.003f, dbl = t2*0.05f, cbl = t3*0.02f;
    o[0]=ebl; o[1]=dbl; o[2]=cbl; o[3]=ebl+dbl+cbl;
  }
}

// ---------------- launch ----------------
extern "C" void kernel_launch(void* const* d_in, const int* in_sizes, int n_in,
                              void* d_out, int out_size, void* d_ws, size_t ws_size,
                              hipStream_t stream){
  const float* x        = (const float*)d_in[0];
  const float* cosb     = (const float*)d_in[1];
  const float* sinb     = (const float*)d_in[2];
  const float* w_qkv    = (const float*)d_in[3];
  const float* w_o      = (const float*)d_in[4];
  const float* router_w = (const float*)d_in[5];
  const float* r_wgu    = (const float*)d_in[6];
  const float* r_wd     = (const float*)d_in[7];
  const float* s_wgu    = (const float*)d_in[8];
  const float* s_wd     = (const float*)d_in[9];
  float* out = (float*)d_out;

  char* base = (char*)d_ws;
  size_t off = 0;
  auto alloc = [&](size_t b)->char*{
    char* p = base + off; off = (off + b + 255) & ~(size_t)255; return p;
  };
  unsigned short* x_hi   = (unsigned short*)alloc(2097152ULL*2);
  unsigned short* x_lo   = (unsigned short*)alloc(2097152ULL*2);
  unsigned short* wqkvT_hi = (unsigned short*)alloc(786432ULL*2);
  unsigned short* wqkvT_lo = (unsigned short*)alloc(786432ULL*2);
  unsigned short* woT_hi = (unsigned short*)alloc(262144ULL*2);
  unsigned short* woT_lo = (unsigned short*)alloc(262144ULL*2);
  unsigned short* wrT_hi = (unsigned short*)alloc(32768ULL*2);
  unsigned short* wrT_lo = (unsigned short*)alloc(32768ULL*2);
  unsigned short* h1_hi  = (unsigned short*)alloc(2097152ULL*2);
  unsigned short* h1_lo  = (unsigned short*)alloc(2097152ULL*2);
  unsigned short* h1b    = (unsigned short*)alloc(2097152ULL*2);
  float* hbuf   = (float*)alloc(2097152ULL*4);
  float* fixo   = (float*)alloc(1024ULL*512*4);
  float* logits = (float*)alloc(262144ULL*4);
  float* probs  = (float*)alloc(262144ULL*4);
  int*   idx    = (int*)alloc(24576ULL*4);
  float* wts    = (float*)alloc(24576ULL*4);
  int*   slot_of= (int*)alloc(24576ULL*4);
  int*   cnt     = (int*)alloc(256);
  int*   cursor  = (int*)alloc(256);
  int*   flagcnt = (int*)alloc(256);
  int*   flaglist= (int*)alloc(1024*4);
  int*   offs   = (int*)alloc(65*4);
  int*   ntl    = (int*)alloc(256);
  float* sumP   = (float*)alloc(64*4);
  int2*  tiles  = (int2*)alloc(512*8);
  int*   rowsl  = (int*)alloc(24576ULL*4);
  float* wrowl  = (float*)alloc(24576ULL*4);
  // attention (un-aliased)
  float* qkv    = (float*)alloc(6291456ULL*4);
  unsigned short* qkv_hi = (unsigned short*)alloc(6291456ULL*2);
  unsigned short* qkv_lo = (unsigned short*)alloc(6291456ULL*2);
  unsigned short* vT_hi  = (unsigned short*)alloc(2097152ULL*2);
  unsigned short* vT_lo  = (unsigned short*)alloc(2097152ULL*2);
  unsigned short* attno_hi = (unsigned short*)alloc(2097152ULL*2);
  unsigned short* attno_lo = (unsigned short*)alloc(2097152ULL*2);
  float* attnw = (float*)alloc(2097152ULL*4);
  // FFN
  unsigned short* wguT = (unsigned short*)alloc(100663296ULL*2);   // [64][3072][512]
  unsigned short* sguT = (unsigned short*)alloc(3145728ULL*2);     // [2][3072][512]
  unsigned short* xg   = (unsigned short*)alloc(12582912ULL*2);    // [24576][512]
  unsigned short* hact = (unsigned short*)alloc(37748736ULL*2);    // [24576][1536]
  unsigned short* shact= (unsigned short*)alloc(12582912ULL*2);    // [2][4096][1536]
  unsigned short* doutb  = (unsigned short*)alloc(12582912ULL*2);  // [24576][512]
  unsigned short* sdoutb = (unsigned short*)alloc(4194304ULL*2);   // [2][4096][512]
  unsigned short* wdT  = (unsigned short*)alloc(50331648ULL*2);    // [64][512][1536]  (FIXED: was 33554432)
  unsigned short* swdT = (unsigned short*)alloc(1572864ULL*2);     // [2][512][1536]

  hipMemsetAsync(cnt, 0, 768, stream);

  ksplit<<<2048, 256, 0, stream>>>(x, x_hi, x_lo, 524288);
  kTsplit<<<dim3(24,8), 256, 0, stream>>>(w_qkv, wqkvT_hi, wqkvT_lo, 512, 1536);
  kTsplit<<<dim3(8,8),  256, 0, stream>>>(w_o, woT_hi, woT_lo, 512, 512);
  kTsplit<<<dim3(1,8),  256, 0, stream>>>(router_w, wrT_hi, wrT_lo, 512, 64);

  gemm_x3<2,2,4,4><<<dim3(32,12,1), 256, 0, stream>>>(x_hi, x_lo, wqkvT_hi, wqkvT_lo,
      qkv, 512, 512, 512, 1536, 1.0f, 0,0,1, 0,0,1, 0,0,1);
  krope<<<4096, 256, 0, stream>>>(qkv, qkv_hi, qkv_lo, cosb, sinb);
  kvtrans<<<dim3(16,32), 256, 0, stream>>>(qkv, vT_hi, vT_lo);

  // fused flash attention -> attno hi/lo
  kflash<<<dim3(16,32), 256, 0, stream>>>(qkv_hi, qkv_lo, vT_hi, vT_lo, attno_hi, attno_lo);

  gemm_x3<2,2,4,4><<<dim3(32,4,1), 256, 0, stream>>>(attno_hi, attno_lo, woT_hi, woT_lo,
      attnw, 512, 512, 512, 512, 1.0f, 0,0,1, 0,0,1, 0,0,1);
  krms1<<<4096, 128, 0, stream>>>(x, attnw, h1_hi, h1_lo, h1b, hbuf);
  gemm_x3<2,2,2,2><<<dim3(64,1,1), 256, 0, stream>>>(h1_hi, h1_lo, wrT_hi, wrT_lo,
      logits, 512, 512, 512, 64, 1.0f, 0,0,1, 0,0,1, 0,0,1);
  krouter<<<1024, 256, 0, stream>>>(logits, probs, idx, wts, cnt, flagcnt, flaglist);
  kfix_attn<<<dim3(1024,8), 256, 0, stream>>>(flagcnt, flaglist, qkv, fixo);
  kfix_route<<<1024, 256, 0, stream>>>(flagcnt, flaglist, fixo, x, w_o, router_w, idx, wts, probs, cnt);
  ksump<<<64, 256, 0, stream>>>(probs, sumP);
  kfinalize<<<1, 64, 0, stream>>>(cnt, offs, tiles, ntl);
  kscatter<<<96, 256, 0, stream>>>(idx, wts, offs, cursor, rowsl, wrowl, slot_of);

  // ---- FFN phase ----
  kgather<<<6144, 256, 0, stream>>>(h1b, rowsl, xg);
  kconvT<true><<<dim3(48,8,64), 256, 0, stream>>>(r_wgu, wguT, 512, 3072);
  kconvT<true><<<dim3(48,8,2),  256, 0, stream>>>(s_wgu, sguT, 512, 3072);
  gemm_ffn<0><<<6144, 256, 0, stream>>>(xg, wguT, hact, offs, tiles, ntl, 3072, 512);
  gemm_ffn<2><<<dim3(32,24,2), 256, 0, stream>>>(h1b, sguT, shact, offs, tiles, ntl, 3072, 512);
  kconvT<false><<<dim3(8,24,64), 256, 0, stream>>>(r_wd, wdT, 1536, 512);
  kconvT<false><<<dim3(8,24,2),  256, 0, stream>>>(s_wd, swdT, 1536, 512);
  gemm_ffn<1><<<1024, 256, 0, stream>>>(hact, wdT, doutb, offs, tiles, ntl, 512, 1536);
  gemm_ffn<3><<<dim3(32,4,2), 256, 0, stream>>>(shact, swdT, sdoutb, offs, tiles, ntl, 512, 1536);

  kreduce<<<4096, 128, 0, stream>>>(hbuf, sdoutb, doutb, slot_of, wts, out);
  kscalars<<<1, 64, 0, stream>>>(cnt, sumP, out + 2097152);
}